// Round 8
// baseline (321.179 us; speedup 1.0000x reference)
//
#include <hip/hip_runtime.h>
#include <math.h>

// Problem constants
#define B_SZ   2
#define SEQ    2048
#define DM     1024
#define NH     16
#define DH     64
#define MROWS  (B_SZ * SEQ)      // 4096
#define DQKV   (3 * DM)          // 3072, interleaved qkv row stride

typedef __attribute__((ext_vector_type(8))) short short8;
typedef __attribute__((ext_vector_type(4))) float f32x4;
typedef __attribute__((ext_vector_type(4))) unsigned short us4;
typedef __attribute__((ext_vector_type(2))) unsigned int u32x2;

__device__ __forceinline__ float b2f(unsigned short u) {
    union { float f; unsigned int i; } x; x.i = ((unsigned int)u) << 16; return x.f;
}
__device__ __forceinline__ unsigned short f2b(float f) {
    union { float f; unsigned int i; } x; x.f = f;
    return (unsigned short)((x.i + 0x7fffu + ((x.i >> 16) & 1u)) >> 16);
}

// async global->LDS, 16B per lane; lds base must be wave-uniform (HW adds lane*16)
__device__ __forceinline__ void gload_lds16(const unsigned short* g, unsigned short* lds_base_uniform) {
    __builtin_amdgcn_global_load_lds(
        (const __attribute__((address_space(1))) unsigned int*)g,
        (__attribute__((address_space(3))) unsigned int*)lds_base_uniform,
        16, 0, 0);
}

// ---------------------------------------------------------------------------
// f32 -> bf16 conversion (vectorized, n % 4 == 0)
// ---------------------------------------------------------------------------
__global__ __launch_bounds__(256) void cvt_f32_bf16(const float* __restrict__ in,
                                                    unsigned short* __restrict__ out, int n) {
    int i = blockIdx.x * blockDim.x + threadIdx.x;
    if (i * 4 >= n) return;
    float4 v = reinterpret_cast<const float4*>(in)[i];
    us4 o = { f2b(v.x), f2b(v.y), f2b(v.z), f2b(v.w) };
    reinterpret_cast<us4*>(out)[i] = o;
}

// 3 weights -> one concatenated bf16 buffer [3*DM][DM]
__global__ __launch_bounds__(256) void cvt3_f32_bf16(const float* __restrict__ a,
                                                     const float* __restrict__ b,
                                                     const float* __restrict__ c,
                                                     unsigned short* __restrict__ out) {
    const int each4 = DM * DM / 4;               // vec4 count per weight
    int i = blockIdx.x * blockDim.x + threadIdx.x;   // [0, 3*each4)
    const float* src = (i < each4) ? a : (i < 2 * each4) ? b : c;
    int off = (i < each4) ? i : (i < 2 * each4) ? i - each4 : i - 2 * each4;
    float4 v = reinterpret_cast<const float4*>(src)[off];
    us4 o = { f2b(v.x), f2b(v.y), f2b(v.z), f2b(v.w) };
    reinterpret_cast<us4*>(out)[i] = o;
}

// ---------------------------------------------------------------------------
// bf16 MFMA GEMM (m97 structure, single-buffered), 128x128 tile, BK=32.
// ---------------------------------------------------------------------------
#define BM 128
#define BN 128
#define BK 32

template <bool BF16OUT>
__global__ __launch_bounds__(256) void gemm_bt_mfma(const unsigned short* __restrict__ A,
                                                    const unsigned short* __restrict__ B,
                                                    void* __restrict__ Cout,
                                                    int M, int N, int K) {
    __shared__ unsigned short As[BM * BK];   // 8 KB
    __shared__ unsigned short Bs[BN * BK];   // 8 KB
    const int tid  = threadIdx.x;
    const int lane = tid & 63, wid = tid >> 6;
    const int wr = wid >> 1, wc = wid & 1;
    const int lm = lane & 15, lg = lane >> 4;
    const int brow = blockIdx.y * BM, bcol = blockIdx.x * BN;

    f32x4 acc[4][4] = {};

    const int rA  = tid >> 2;
    const int kc8 = (tid & 3) * 8;
    const unsigned short* gA0 = A + (size_t)(brow + rA) * K + kc8;
    const unsigned short* gA1 = A + (size_t)(brow + 64 + rA) * K + kc8;
    const unsigned short* gB0 = B + (size_t)(bcol + rA) * K + kc8;
    const unsigned short* gB1 = B + (size_t)(bcol + 64 + rA) * K + kc8;
    unsigned short* lA0 = As + wid * 512;
    unsigned short* lA1 = As + 2048 + wid * 512;
    unsigned short* lB0 = Bs + wid * 512;
    unsigned short* lB1 = Bs + 2048 + wid * 512;

    for (int k0 = 0; k0 < K; k0 += BK) {
        gload_lds16(gA0 + k0, lA0);
        gload_lds16(gA1 + k0, lA1);
        gload_lds16(gB0 + k0, lB0);
        gload_lds16(gB1 + k0, lB1);
        __syncthreads();

        short8 a[4], b[4];
#pragma unroll
        for (int m = 0; m < 4; ++m)
            a[m] = *reinterpret_cast<const short8*>(&As[(wr * 64 + m * 16 + lm) * BK + lg * 8]);
#pragma unroll
        for (int n = 0; n < 4; ++n)
            b[n] = *reinterpret_cast<const short8*>(&Bs[(wc * 64 + n * 16 + lm) * BK + lg * 8]);
#pragma unroll
        for (int m = 0; m < 4; ++m)
#pragma unroll
            for (int n = 0; n < 4; ++n)
                acc[m][n] = __builtin_amdgcn_mfma_f32_16x16x32_bf16(a[m], b[n], acc[m][n], 0, 0, 0);
        __syncthreads();
    }

#pragma unroll
    for (int m = 0; m < 4; ++m) {
#pragma unroll
        for (int r = 0; r < 4; ++r) {
            const size_t base = (size_t)(brow + wr * 64 + m * 16 + lg * 4 + r) * N + bcol + wc * 64 + lm;
#pragma unroll
            for (int n = 0; n < 4; ++n) {
                if (BF16OUT)
                    ((unsigned short*)Cout)[base + n * 16] = f2b(acc[m][n][r]);
                else
                    ((float*)Cout)[base + n * 16] = acc[m][n][r];
            }
        }
    }
}

// ---------------------------------------------------------------------------
// RoPE in place on interleaved qkv (q at col 0.., k at col 1024..).
// One s per block; 32 cos/sin computed into LDS. q scaled by log2(e)/8.
// ---------------------------------------------------------------------------
__global__ __launch_bounds__(256) void rope_qk_bf16(unsigned short* __restrict__ qkv) {
    __shared__ float cs_c[32], cs_s[32];
    const int tid = threadIdx.x;
    const int row = blockIdx.x >> 1;              // [0, MROWS)
    const int s   = row & (SEQ - 1);
    if (tid < 32) {
        float inv = powf(10000.0f, -(float)tid / 32.0f);
        float ang = (float)s * inv;
        cs_c[tid] = cosf(ang);
        cs_s[tid] = sinf(ang);
    }
    __syncthreads();
    const int idx = blockIdx.x * 256 + tid;
    const int i = idx & 31;
    const int h = (idx >> 5) & 15;
    const float c = cs_c[i], sn = cs_s[i];
    const size_t off = (size_t)row * DQKV + h * 64 + 2 * i;
    const float scale = 0.125f * 1.4426950408889634f;   // 1/sqrt(64) * log2(e)
    float qe = b2f(qkv[off]), qo = b2f(qkv[off + 1]);
    qkv[off]     = f2b((qe * c - qo * sn) * scale);
    qkv[off + 1] = f2b((qe * sn + qo * c) * scale);
    float ke = b2f(qkv[off + DM]), ko = b2f(qkv[off + DM + 1]);
    qkv[off + DM]     = f2b(ke * c - ko * sn);
    qkv[off + DM + 1] = f2b(ke * sn + ko * c);
}

// ---------------------------------------------------------------------------
// Transpose V (qkv cols 2048..3071): -> vT[(b*NH+h)*DH + d][s]   (bf16)
// ---------------------------------------------------------------------------
__global__ __launch_bounds__(256) void transpose_v(const unsigned short* __restrict__ qkv,
                                                   unsigned short* __restrict__ vT) {
    __shared__ unsigned short t[64][68];
    const int s0 = blockIdx.x * 64;
    const int bh = blockIdx.y;
    const int b = bh >> 4, h = bh & 15;
    const int tid = threadIdx.x;
    for (int idx = tid; idx < 1024; idx += 256) {
        int s = idx >> 4;
        int dg = (idx & 15) * 4;
        us4 val = *reinterpret_cast<const us4*>(qkv + (size_t)(b * SEQ + s0 + s) * DQKV + 2 * DM + h * DH + dg);
        *reinterpret_cast<us4*>(&t[s][dg]) = val;
    }
    __syncthreads();
    for (int idx = tid; idx < 1024; idx += 256) {
        int d = idx >> 4;
        int sg = (idx & 15) * 4;
        us4 val;
        val.x = t[sg + 0][d];
        val.y = t[sg + 1][d];
        val.z = t[sg + 2][d];
        val.w = t[sg + 3][d];
        *reinterpret_cast<us4*>(vT + (size_t)(bh * DH + d) * SEQ + s0 + sg) = val;
    }
}

// ---------------------------------------------------------------------------
// MFMA flash attention v6: swapped QK^T + in-register softmax + defer-max.
// One 16-row q-tile per wave; block's 4 waves take CONSECUTIVE tiles
// {p..p+3} (trip counts differ <=1 -> no intra-block wave idle); tile
// groups ordered longest-first. XCD swizzle: 4 bh per XCD.
// Defer-max: skip cross-lane max reduce + O rescale while
// __all(in-lane max - running max <= 8) (P bounded by 2^8, fp32 l).
// setprio(1) wrapped around MFMA clusters (T5, independent-wave regime).
// ---------------------------------------------------------------------------
#define LOADK(kbase, dst)                                                              \
    {                                                                                  \
        _Pragma("unroll")                                                              \
        for (int st = 0; st < 4; ++st) {                                               \
            const unsigned short* kr = kb + (size_t)((kbase) + st * 16 + lm) * DQKV;   \
            dst[st * 2]     = *reinterpret_cast<const short8*>(kr + lg * 8);           \
            dst[st * 2 + 1] = *reinterpret_cast<const short8*>(kr + 32 + lg * 8);      \
        }                                                                              \
    }

__global__ __launch_bounds__(256, 4) void attn_mfma(const unsigned short* __restrict__ qkv,
                                                    const unsigned short* __restrict__ vT,
                                                    unsigned short* __restrict__ o) {
    const int tid  = threadIdx.x;
    const int wid  = tid >> 6;
    const int lane = tid & 63;
    const int lm = lane & 15, lg = lane >> 4;

    const int bid = blockIdx.x;             // [0,1024)
    const int u   = bid >> 3;               // [0,128)
    const int g   = u & 31;                 // tile group within bh
    const int bh  = (bid & 7) + 8 * (u >> 5);
    const int p   = (31 - g) * 4 + wid;     // longest groups first; waves consecutive
    const int b = bh >> 4, h = bh & 15;
    const int qbase = p * 16;

    __shared__ unsigned int Pex[4][16 * 34];   // per-wave P exchange (8.5 KB)
    unsigned int* PW = Pex[wid];

    const unsigned short* kb = qkv + ((size_t)b * SEQ) * DQKV + DM + h * DH;
    const unsigned short* vb = vT + ((size_t)bh) * DH * SEQ;

    const int wr_base = lm * 34 + lg * 2;                       // + st*8
    const int rd1 = lm * 34 + (lg >> 1) * 8 + (lg & 1) * 4;     // PV1 dwords
    const int rd2 = rd1 + 16;                                    // PV2 (st+2)

    const unsigned short* qrow = qkv + ((size_t)(b * SEQ + qbase + lm)) * DQKV + h * DH;
    short8 qa0 = *reinterpret_cast<const short8*>(qrow + lg * 8);
    short8 qa1 = *reinterpret_cast<const short8*>(qrow + 32 + lg * 8);

    f32x4 o0 = {0.f, 0.f, 0.f, 0.f}, o1 = o0, o2 = o0, o3 = o0;
    float mrun = -INFINITY, lrun = 0.f;

    const int nb = (qbase + 79) >> 6;
    short8 kc[8];
    LOADK(0, kc);

    for (int blk = 0; blk < nb; ++blk) {
        const int kbase = blk << 6;

        // V loads issued early (consumed at PV, hidden under QK+softmax)
        short8 vv[8];
#pragma unroll
        for (int c = 0; c < 4; ++c) {
            const unsigned short* vr = vb + (size_t)(c * 16 + lm) * SEQ + kbase;
            vv[c * 2]     = *reinterpret_cast<const short8*>(vr + lg * 8);
            vv[c * 2 + 1] = *reinterpret_cast<const short8*>(vr + 32 + lg * 8);
        }

        // QK^T swapped: S^T[k][q]
        float s[16];
        __builtin_amdgcn_s_setprio(1);
#pragma unroll
        for (int st = 0; st < 4; ++st) {
            f32x4 t = {0.f, 0.f, 0.f, 0.f};
            t = __builtin_amdgcn_mfma_f32_16x16x32_bf16(kc[st * 2],     qa0, t, 0, 0, 0);
            t = __builtin_amdgcn_mfma_f32_16x16x32_bf16(kc[st * 2 + 1], qa1, t, 0, 0, 0);
#pragma unroll
            for (int r = 0; r < 4; ++r) s[st * 4 + r] = t[r];
        }
        __builtin_amdgcn_s_setprio(0);

        // prefetch next K (consumed next iteration)
        if (blk + 1 < nb) LOADK((blk + 1) << 6, kc);

        // causal mask (last block only crosses the diagonal)
        if (blk == nb - 1) {
#pragma unroll
            for (int st = 0; st < 4; ++st)
#pragma unroll
                for (int r = 0; r < 4; ++r) {
                    int kk = kbase + st * 16 + lg * 4 + r;
                    s[st * 4 + r] = (kk <= qbase + lm) ? s[st * 4 + r] : -INFINITY;
                }
        }

        // in-lane max over this lane's 16 scores
        float t0 = fmaxf(s[0], s[1]),  t1 = fmaxf(s[2], s[3]);
        float t2 = fmaxf(s[4], s[5]),  t3 = fmaxf(s[6], s[7]);
        float t4 = fmaxf(s[8], s[9]),  t5 = fmaxf(s[10], s[11]);
        float t6 = fmaxf(s[12], s[13]), t7 = fmaxf(s[14], s[15]);
        float lmax = fmaxf(fmaxf(fmaxf(t0, t1), fmaxf(t2, t3)),
                           fmaxf(fmaxf(t4, t5), fmaxf(t6, t7)));

        // defer-max: only do cross-lane reduce + rescale when needed
        // (NaN from -inf - -inf compares false -> triggers full path)
        if (!__all(lmax - mrun <= 8.0f)) {
            float mx = lmax;
            mx = fmaxf(mx, __shfl_xor(mx, 16));
            mx = fmaxf(mx, __shfl_xor(mx, 32));
            float mn  = fmaxf(mrun, mx);
            float fsc = exp2f(mrun - mn);
            mrun = mn;
            lrun *= fsc;
            float fr[4];
#pragma unroll
            for (int r = 0; r < 4; ++r) fr[r] = __shfl(fsc, lg * 4 + r);
#pragma unroll
            for (int r = 0; r < 4; ++r) {
                o0[r] *= fr[r]; o1[r] *= fr[r]; o2[r] *= fr[r]; o3[r] *= fr[r];
            }
        }

        // P = exp2(S - mrun); sum feeds only lrun (off critical path)
#pragma unroll
        for (int i = 0; i < 16; ++i) s[i] = exp2f(s[i] - mrun);
        float a0 = (s[0] + s[1]) + (s[2] + s[3]);
        float a1 = (s[4] + s[5]) + (s[6] + s[7]);
        float a2 = (s[8] + s[9]) + (s[10] + s[11]);
        float a3 = (s[12] + s[13]) + (s[14] + s[15]);
        float ps = (a0 + a1) + (a2 + a3);
        ps += __shfl_xor(ps, 16);
        ps += __shfl_xor(ps, 32);
        lrun += ps;

        // pack P (round-to-nearest bf16) and relayout through LDS
#pragma unroll
        for (int st = 0; st < 4; ++st) {
            union { float f; unsigned int u; } e0, e1, e2, e3;
            e0.f = s[st * 4 + 0]; e1.f = s[st * 4 + 1];
            e2.f = s[st * 4 + 2]; e3.f = s[st * 4 + 3];
            u32x2 w;
            w.x = ((e0.u + 0x8000u) >> 16) | ((e1.u + 0x8000u) & 0xFFFF0000u);
            w.y = ((e2.u + 0x8000u) >> 16) | ((e3.u + 0x8000u) & 0xFFFF0000u);
            *reinterpret_cast<u32x2*>(&PW[wr_base + st * 8]) = w;
        }
        __builtin_amdgcn_wave_barrier();
        asm volatile("" ::: "memory");

        union { unsigned int u[4]; short8 v; } pk1, pk2;
        {
            u32x2 x0 = *reinterpret_cast<const u32x2*>(&PW[rd1]);
            u32x2 x1 = *reinterpret_cast<const u32x2*>(&PW[rd1 + 2]);
            pk1.u[0] = x0.x; pk1.u[1] = x0.y; pk1.u[2] = x1.x; pk1.u[3] = x1.y;
            u32x2 y0 = *reinterpret_cast<const u32x2*>(&PW[rd2]);
            u32x2 y1 = *reinterpret_cast<const u32x2*>(&PW[rd2 + 2]);
            pk2.u[0] = y0.x; pk2.u[1] = y0.y; pk2.u[2] = y1.x; pk2.u[3] = y1.y;
        }
        __builtin_amdgcn_wave_barrier();
        asm volatile("" ::: "memory");

        // PV: O[q = lg*4+r][d = lm + 16c]
        __builtin_amdgcn_s_setprio(1);
        o0 = __builtin_amdgcn_mfma_f32_16x16x32_bf16(pk1.v, vv[0], o0, 0, 0, 0);
        o0 = __builtin_amdgcn_mfma_f32_16x16x32_bf16(pk2.v, vv[1], o0, 0, 0, 0);
        o1 = __builtin_amdgcn_mfma_f32_16x16x32_bf16(pk1.v, vv[2], o1, 0, 0, 0);
        o1 = __builtin_amdgcn_mfma_f32_16x16x32_bf16(pk2.v, vv[3], o1, 0, 0, 0);
        o2 = __builtin_amdgcn_mfma_f32_16x16x32_bf16(pk1.v, vv[4], o2, 0, 0, 0);
        o2 = __builtin_amdgcn_mfma_f32_16x16x32_bf16(pk2.v, vv[5], o2, 0, 0, 0);
        o3 = __builtin_amdgcn_mfma_f32_16x16x32_bf16(pk1.v, vv[6], o3, 0, 0, 0);
        o3 = __builtin_amdgcn_mfma_f32_16x16x32_bf16(pk2.v, vv[7], o3, 0, 0, 0);
        __builtin_amdgcn_s_setprio(0);
    }

    // epilogue: fetch l for output rows, normalize, store bf16
    float linv[4];
#pragma unroll
    for (int r = 0; r < 4; ++r) linv[r] = 1.0f / __shfl(lrun, lg * 4 + r);
#pragma unroll
    for (int r = 0; r < 4; ++r) {
        const size_t rowoff = ((size_t)(b * SEQ + qbase + lg * 4 + r)) * DM + h * DH;
        o[rowoff + 0 * 16 + lm] = f2b(o0[r] * linv[r]);
        o[rowoff + 1 * 16 + lm] = f2b(o1[r] * linv[r]);
        o[rowoff + 2 * 16 + lm] = f2b(o2[r] * linv[r]);
        o[rowoff + 3 * 16 + lm] = f2b(o3[r] * linv[r]);
    }
}

// ---------------------------------------------------------------------------
extern "C" void kernel_launch(void* const* d_in, const int* in_sizes, int n_in,
                              void* d_out, int out_size, void* d_ws, size_t ws_size,
                              hipStream_t stream) {
    const float* x  = (const float*)d_in[0];
    const float* wq = (const float*)d_in[1];
    const float* wk = (const float*)d_in[2];
    const float* wv = (const float*)d_in[3];
    const float* wo = (const float*)d_in[4];
    float* out = (float*)d_out;

    const int TSZ = MROWS * DM;      // 4M
    const int WSZ = DM * DM;         // 1M
    char* ws = (char*)d_ws;
    const size_t MB = 1024 * 1024;
    unsigned short* xb      = (unsigned short*)(ws);             // 8 MB  (reused for attn_bf)
    unsigned short* wqkv    = (unsigned short*)(ws + 8 * MB);    // 6 MB
    unsigned short* wob     = (unsigned short*)(ws + 14 * MB);   // 2 MB
    unsigned short* qkv     = (unsigned short*)(ws + 16 * MB);   // 24 MB (interleaved q|k|v)
    unsigned short* vT      = (unsigned short*)(ws + 40 * MB);   // 8 MB
    unsigned short* attn_bf = xb;                                // xb dead after QKV GEMM

    cvt_f32_bf16<<<TSZ / 4 / 256, 256, 0, stream>>>(x, xb, TSZ);
    cvt3_f32_bf16<<<3 * WSZ / 4 / 256, 256, 0, stream>>>(wq, wk, wv, wqkv);
    cvt_f32_bf16<<<WSZ / 4 / 256, 256, 0, stream>>>(wo, wob, WSZ);

    // fused QKV GEMM: (4096 x 1024) x (3072 x 1024)^T -> qkv interleaved
    gemm_bt_mfma<true><<<dim3(DQKV / BN, MROWS / BM), 256, 0, stream>>>(xb, wqkv, qkv, MROWS, DQKV, DM);

    rope_qk_bf16<<<MROWS * 2, 256, 0, stream>>>(qkv);

    transpose_v<<<dim3(SEQ / 64, B_SZ * NH), 256, 0, stream>>>(qkv, vT);

    attn_mfma<<<1024, 256, 0, stream>>>(qkv, vT, attn_bf);

    gemm_bt_mfma<false><<<dim3(DM / BN, MROWS / BM), 256, 0, stream>>>(attn_bf, wob, out, MROWS, DM, DM);
}

// Round 9
// 214.764 us; speedup vs baseline: 1.4955x; 1.4955x over previous
//
#include <hip/hip_runtime.h>
#include <math.h>

// Problem constants
#define B_SZ   2
#define SEQ    2048
#define DM     1024
#define NH     16
#define DH     64
#define MROWS  (B_SZ * SEQ)      // 4096
#define DQKV   (3 * DM)          // 3072, interleaved qkv row stride

typedef __attribute__((ext_vector_type(8))) short short8;
typedef __attribute__((ext_vector_type(4))) float f32x4;
typedef __attribute__((ext_vector_type(4))) unsigned short us4;
typedef __attribute__((ext_vector_type(2))) unsigned int u32x2;

__device__ __forceinline__ float b2f(unsigned short u) {
    union { float f; unsigned int i; } x; x.i = ((unsigned int)u) << 16; return x.f;
}
__device__ __forceinline__ unsigned short f2b(float f) {
    union { float f; unsigned int i; } x; x.f = f;
    return (unsigned short)((x.i + 0x7fffu + ((x.i >> 16) & 1u)) >> 16);
}

// async global->LDS, 16B per lane; lds base must be wave-uniform (HW adds lane*16)
__device__ __forceinline__ void gload_lds16(const unsigned short* g, unsigned short* lds_base_uniform) {
    __builtin_amdgcn_global_load_lds(
        (const __attribute__((address_space(1))) unsigned int*)g,
        (__attribute__((address_space(3))) unsigned int*)lds_base_uniform,
        16, 0, 0);
}

// ---------------------------------------------------------------------------
// f32 -> bf16 conversion (vectorized, n % 4 == 0)
// ---------------------------------------------------------------------------
__global__ __launch_bounds__(256) void cvt_f32_bf16(const float* __restrict__ in,
                                                    unsigned short* __restrict__ out, int n) {
    int i = blockIdx.x * blockDim.x + threadIdx.x;
    if (i * 4 >= n) return;
    float4 v = reinterpret_cast<const float4*>(in)[i];
    us4 o = { f2b(v.x), f2b(v.y), f2b(v.z), f2b(v.w) };
    reinterpret_cast<us4*>(out)[i] = o;
}

// 3 weights -> one concatenated bf16 buffer [3*DM][DM]
__global__ __launch_bounds__(256) void cvt3_f32_bf16(const float* __restrict__ a,
                                                     const float* __restrict__ b,
                                                     const float* __restrict__ c,
                                                     unsigned short* __restrict__ out) {
    const int each4 = DM * DM / 4;               // vec4 count per weight
    int i = blockIdx.x * blockDim.x + threadIdx.x;   // [0, 3*each4)
    const float* src = (i < each4) ? a : (i < 2 * each4) ? b : c;
    int off = (i < each4) ? i : (i < 2 * each4) ? i - each4 : i - 2 * each4;
    float4 v = reinterpret_cast<const float4*>(src)[off];
    us4 o = { f2b(v.x), f2b(v.y), f2b(v.z), f2b(v.w) };
    reinterpret_cast<us4*>(out)[i] = o;
}

// ---------------------------------------------------------------------------
// bf16 MFMA GEMM (m97 structure, single-buffered), 128x128 tile, BK=32.
// ---------------------------------------------------------------------------
#define BM 128
#define BN 128
#define BK 32

template <bool BF16OUT>
__global__ __launch_bounds__(256) void gemm_bt_mfma(const unsigned short* __restrict__ A,
                                                    const unsigned short* __restrict__ B,
                                                    void* __restrict__ Cout,
                                                    int M, int N, int K) {
    __shared__ unsigned short As[BM * BK];   // 8 KB
    __shared__ unsigned short Bs[BN * BK];   // 8 KB
    const int tid  = threadIdx.x;
    const int lane = tid & 63, wid = tid >> 6;
    const int wr = wid >> 1, wc = wid & 1;
    const int lm = lane & 15, lg = lane >> 4;
    const int brow = blockIdx.y * BM, bcol = blockIdx.x * BN;

    f32x4 acc[4][4] = {};

    const int rA  = tid >> 2;
    const int kc8 = (tid & 3) * 8;
    const unsigned short* gA0 = A + (size_t)(brow + rA) * K + kc8;
    const unsigned short* gA1 = A + (size_t)(brow + 64 + rA) * K + kc8;
    const unsigned short* gB0 = B + (size_t)(bcol + rA) * K + kc8;
    const unsigned short* gB1 = B + (size_t)(bcol + 64 + rA) * K + kc8;
    unsigned short* lA0 = As + wid * 512;
    unsigned short* lA1 = As + 2048 + wid * 512;
    unsigned short* lB0 = Bs + wid * 512;
    unsigned short* lB1 = Bs + 2048 + wid * 512;

    for (int k0 = 0; k0 < K; k0 += BK) {
        gload_lds16(gA0 + k0, lA0);
        gload_lds16(gA1 + k0, lA1);
        gload_lds16(gB0 + k0, lB0);
        gload_lds16(gB1 + k0, lB1);
        __syncthreads();

        short8 a[4], b[4];
#pragma unroll
        for (int m = 0; m < 4; ++m)
            a[m] = *reinterpret_cast<const short8*>(&As[(wr * 64 + m * 16 + lm) * BK + lg * 8]);
#pragma unroll
        for (int n = 0; n < 4; ++n)
            b[n] = *reinterpret_cast<const short8*>(&Bs[(wc * 64 + n * 16 + lm) * BK + lg * 8]);
#pragma unroll
        for (int m = 0; m < 4; ++m)
#pragma unroll
            for (int n = 0; n < 4; ++n)
                acc[m][n] = __builtin_amdgcn_mfma_f32_16x16x32_bf16(a[m], b[n], acc[m][n], 0, 0, 0);
        __syncthreads();
    }

#pragma unroll
    for (int m = 0; m < 4; ++m) {
#pragma unroll
        for (int r = 0; r < 4; ++r) {
            const size_t base = (size_t)(brow + wr * 64 + m * 16 + lg * 4 + r) * N + bcol + wc * 64 + lm;
#pragma unroll
            for (int n = 0; n < 4; ++n) {
                if (BF16OUT)
                    ((unsigned short*)Cout)[base + n * 16] = f2b(acc[m][n][r]);
                else
                    ((float*)Cout)[base + n * 16] = acc[m][n][r];
            }
        }
    }
}

// ---------------------------------------------------------------------------
// RoPE in place on interleaved qkv (q at col 0.., k at col 1024..).
// One s per block; 32 cos/sin computed into LDS. q scaled by log2(e)/8.
// ---------------------------------------------------------------------------
__global__ __launch_bounds__(256) void rope_qk_bf16(unsigned short* __restrict__ qkv) {
    __shared__ float cs_c[32], cs_s[32];
    const int tid = threadIdx.x;
    const int row = blockIdx.x >> 1;              // [0, MROWS)
    const int s   = row & (SEQ - 1);
    if (tid < 32) {
        float inv = powf(10000.0f, -(float)tid / 32.0f);
        float ang = (float)s * inv;
        cs_c[tid] = cosf(ang);
        cs_s[tid] = sinf(ang);
    }
    __syncthreads();
    const int idx = blockIdx.x * 256 + tid;
    const int i = idx & 31;
    const int h = (idx >> 5) & 15;
    const float c = cs_c[i], sn = cs_s[i];
    const size_t off = (size_t)row * DQKV + h * 64 + 2 * i;
    const float scale = 0.125f * 1.4426950408889634f;   // 1/sqrt(64) * log2(e)
    float qe = b2f(qkv[off]), qo = b2f(qkv[off + 1]);
    qkv[off]     = f2b((qe * c - qo * sn) * scale);
    qkv[off + 1] = f2b((qe * sn + qo * c) * scale);
    float ke = b2f(qkv[off + DM]), ko = b2f(qkv[off + DM + 1]);
    qkv[off + DM]     = f2b(ke * c - ko * sn);
    qkv[off + DM + 1] = f2b(ke * sn + ko * c);
}

// ---------------------------------------------------------------------------
// Transpose V (qkv cols 2048..3071): -> vT[(b*NH+h)*DH + d][s]   (bf16)
// ---------------------------------------------------------------------------
__global__ __launch_bounds__(256) void transpose_v(const unsigned short* __restrict__ qkv,
                                                   unsigned short* __restrict__ vT) {
    __shared__ unsigned short t[64][68];
    const int s0 = blockIdx.x * 64;
    const int bh = blockIdx.y;
    const int b = bh >> 4, h = bh & 15;
    const int tid = threadIdx.x;
    for (int idx = tid; idx < 1024; idx += 256) {
        int s = idx >> 4;
        int dg = (idx & 15) * 4;
        us4 val = *reinterpret_cast<const us4*>(qkv + (size_t)(b * SEQ + s0 + s) * DQKV + 2 * DM + h * DH + dg);
        *reinterpret_cast<us4*>(&t[s][dg]) = val;
    }
    __syncthreads();
    for (int idx = tid; idx < 1024; idx += 256) {
        int d = idx >> 4;
        int sg = (idx & 15) * 4;
        us4 val;
        val.x = t[sg + 0][d];
        val.y = t[sg + 1][d];
        val.z = t[sg + 2][d];
        val.w = t[sg + 3][d];
        *reinterpret_cast<us4*>(vT + (size_t)(bh * DH + d) * SEQ + s0 + sg) = val;
    }
}

// ---------------------------------------------------------------------------
// MFMA flash attention v7 = v4 pairing structure + defer-max + setprio.
// 512 blocks x 4 waves; each wave processes tiles (127-p) then p -> every
// wave-job is ~33 iterations (flat load, no stragglers).
// XCD swizzle: bh & 7 == bid & 7 (4 bh per XCD, K/V L2-resident).
// Swapped QK^T (S^T = mfma(K,Q)) -> in-register softmax, lane = one q col.
// Defer-max (T13): skip cross-lane max + O-rescale while
// __all(in-lane max - mrun <= 8); NaN (-inf - -inf) falls to full path.
// ---------------------------------------------------------------------------
#define LOADK(kbase, dst)                                                              \
    {                                                                                  \
        _Pragma("unroll")                                                              \
        for (int st = 0; st < 4; ++st) {                                               \
            const unsigned short* kr = kb + (size_t)((kbase) + st * 16 + lm) * DQKV;   \
            dst[st * 2]     = *reinterpret_cast<const short8*>(kr + lg * 8);           \
            dst[st * 2 + 1] = *reinterpret_cast<const short8*>(kr + 32 + lg * 8);      \
        }                                                                              \
    }

__global__ __launch_bounds__(256, 3) void attn_mfma(const unsigned short* __restrict__ qkv,
                                                    const unsigned short* __restrict__ vT,
                                                    unsigned short* __restrict__ o) {
    const int tid  = threadIdx.x;
    const int wid  = tid >> 6;
    const int lane = tid & 63;
    const int lm = lane & 15, lg = lane >> 4;

    const int bid = blockIdx.x;             // [0,512)
    const int u   = bid >> 3;               // [0,64)
    const int bh  = (bid & 7) + 8 * (u >> 4);
    const int p   = (u & 15) * 4 + wid;     // pair index [0,64)
    const int b = bh >> 4, h = bh & 15;

    __shared__ unsigned int Pex[4][16 * 34];   // per-wave P exchange (8.5 KB)
    unsigned int* PW = Pex[wid];

    const unsigned short* kb = qkv + ((size_t)b * SEQ) * DQKV + DM + h * DH;
    const unsigned short* vb = vT + ((size_t)bh) * DH * SEQ;

    const int wr_base = lm * 34 + lg * 2;                       // + st*8
    const int rd1 = lm * 34 + (lg >> 1) * 8 + (lg & 1) * 4;     // PV1 dwords
    const int rd2 = rd1 + 16;                                    // PV2 (st+2)

    for (int half = 0; half < 2; ++half) {
        const int qbase = (half == 0 ? (127 - p) : p) * 16;

        const unsigned short* qrow = qkv + ((size_t)(b * SEQ + qbase + lm)) * DQKV + h * DH;
        short8 qa0 = *reinterpret_cast<const short8*>(qrow + lg * 8);
        short8 qa1 = *reinterpret_cast<const short8*>(qrow + 32 + lg * 8);

        f32x4 o0 = {0.f, 0.f, 0.f, 0.f}, o1 = o0, o2 = o0, o3 = o0;
        float mrun = -INFINITY, lrun = 0.f;

        const int nb = (qbase + 79) >> 6;
        short8 kc[8];
        LOADK(0, kc);

        for (int blk = 0; blk < nb; ++blk) {
            const int kbase = blk << 6;

            // V loads issued early (consumed at PV, hidden under QK+softmax)
            short8 vv[8];
#pragma unroll
            for (int c = 0; c < 4; ++c) {
                const unsigned short* vr = vb + (size_t)(c * 16 + lm) * SEQ + kbase;
                vv[c * 2]     = *reinterpret_cast<const short8*>(vr + lg * 8);
                vv[c * 2 + 1] = *reinterpret_cast<const short8*>(vr + 32 + lg * 8);
            }

            // QK^T swapped: S^T[k][q]
            float s[16];
            __builtin_amdgcn_s_setprio(1);
#pragma unroll
            for (int st = 0; st < 4; ++st) {
                f32x4 t = {0.f, 0.f, 0.f, 0.f};
                t = __builtin_amdgcn_mfma_f32_16x16x32_bf16(kc[st * 2],     qa0, t, 0, 0, 0);
                t = __builtin_amdgcn_mfma_f32_16x16x32_bf16(kc[st * 2 + 1], qa1, t, 0, 0, 0);
#pragma unroll
                for (int r = 0; r < 4; ++r) s[st * 4 + r] = t[r];
            }
            __builtin_amdgcn_s_setprio(0);

            // prefetch next K (consumed next iteration)
            if (blk + 1 < nb) LOADK((blk + 1) << 6, kc);

            // causal mask (last block only crosses the diagonal)
            if (blk == nb - 1) {
#pragma unroll
                for (int st = 0; st < 4; ++st)
#pragma unroll
                    for (int r = 0; r < 4; ++r) {
                        int kk = kbase + st * 16 + lg * 4 + r;
                        s[st * 4 + r] = (kk <= qbase + lm) ? s[st * 4 + r] : -INFINITY;
                    }
            }

            // in-lane max over this lane's 16 scores
            float t0 = fmaxf(s[0], s[1]),  t1 = fmaxf(s[2], s[3]);
            float t2 = fmaxf(s[4], s[5]),  t3 = fmaxf(s[6], s[7]);
            float t4 = fmaxf(s[8], s[9]),  t5 = fmaxf(s[10], s[11]);
            float t6 = fmaxf(s[12], s[13]), t7 = fmaxf(s[14], s[15]);
            float lmax = fmaxf(fmaxf(fmaxf(t0, t1), fmaxf(t2, t3)),
                               fmaxf(fmaxf(t4, t5), fmaxf(t6, t7)));

            // defer-max: cross-lane reduce + rescale only when needed
            if (!__all(lmax - mrun <= 8.0f)) {
                float mx = lmax;
                mx = fmaxf(mx, __shfl_xor(mx, 16));
                mx = fmaxf(mx, __shfl_xor(mx, 32));
                float mn  = fmaxf(mrun, mx);
                float fsc = exp2f(mrun - mn);
                mrun = mn;
                lrun *= fsc;
                float fr[4];
#pragma unroll
                for (int r = 0; r < 4; ++r) fr[r] = __shfl(fsc, lg * 4 + r);
#pragma unroll
                for (int r = 0; r < 4; ++r) {
                    o0[r] *= fr[r]; o1[r] *= fr[r]; o2[r] *= fr[r]; o3[r] *= fr[r];
                }
            }

            // P = exp2(S - mrun); sum feeds only lrun (off critical path)
#pragma unroll
            for (int i = 0; i < 16; ++i) s[i] = exp2f(s[i] - mrun);
            float a0 = (s[0] + s[1]) + (s[2] + s[3]);
            float a1 = (s[4] + s[5]) + (s[6] + s[7]);
            float a2 = (s[8] + s[9]) + (s[10] + s[11]);
            float a3 = (s[12] + s[13]) + (s[14] + s[15]);
            float ps = (a0 + a1) + (a2 + a3);
            ps += __shfl_xor(ps, 16);
            ps += __shfl_xor(ps, 32);
            lrun += ps;

            // pack P (round-to-nearest bf16) and relayout through LDS
#pragma unroll
            for (int st = 0; st < 4; ++st) {
                union { float f; unsigned int u; } e0, e1, e2, e3;
                e0.f = s[st * 4 + 0]; e1.f = s[st * 4 + 1];
                e2.f = s[st * 4 + 2]; e3.f = s[st * 4 + 3];
                u32x2 w;
                w.x = ((e0.u + 0x8000u) >> 16) | ((e1.u + 0x8000u) & 0xFFFF0000u);
                w.y = ((e2.u + 0x8000u) >> 16) | ((e3.u + 0x8000u) & 0xFFFF0000u);
                *reinterpret_cast<u32x2*>(&PW[wr_base + st * 8]) = w;
            }
            __builtin_amdgcn_wave_barrier();
            asm volatile("" ::: "memory");

            union { unsigned int u[4]; short8 v; } pk1, pk2;
            {
                u32x2 x0 = *reinterpret_cast<const u32x2*>(&PW[rd1]);
                u32x2 x1 = *reinterpret_cast<const u32x2*>(&PW[rd1 + 2]);
                pk1.u[0] = x0.x; pk1.u[1] = x0.y; pk1.u[2] = x1.x; pk1.u[3] = x1.y;
                u32x2 y0 = *reinterpret_cast<const u32x2*>(&PW[rd2]);
                u32x2 y1 = *reinterpret_cast<const u32x2*>(&PW[rd2 + 2]);
                pk2.u[0] = y0.x; pk2.u[1] = y0.y; pk2.u[2] = y1.x; pk2.u[3] = y1.y;
            }
            __builtin_amdgcn_wave_barrier();
            asm volatile("" ::: "memory");

            // PV: O[q = lg*4+r][d = lm + 16c]
            __builtin_amdgcn_s_setprio(1);
            o0 = __builtin_amdgcn_mfma_f32_16x16x32_bf16(pk1.v, vv[0], o0, 0, 0, 0);
            o0 = __builtin_amdgcn_mfma_f32_16x16x32_bf16(pk2.v, vv[1], o0, 0, 0, 0);
            o1 = __builtin_amdgcn_mfma_f32_16x16x32_bf16(pk1.v, vv[2], o1, 0, 0, 0);
            o1 = __builtin_amdgcn_mfma_f32_16x16x32_bf16(pk2.v, vv[3], o1, 0, 0, 0);
            o2 = __builtin_amdgcn_mfma_f32_16x16x32_bf16(pk1.v, vv[4], o2, 0, 0, 0);
            o2 = __builtin_amdgcn_mfma_f32_16x16x32_bf16(pk2.v, vv[5], o2, 0, 0, 0);
            o3 = __builtin_amdgcn_mfma_f32_16x16x32_bf16(pk1.v, vv[6], o3, 0, 0, 0);
            o3 = __builtin_amdgcn_mfma_f32_16x16x32_bf16(pk2.v, vv[7], o3, 0, 0, 0);
            __builtin_amdgcn_s_setprio(0);
        }

        // epilogue: fetch l for output rows, normalize, store bf16
        float linv[4];
#pragma unroll
        for (int r = 0; r < 4; ++r) linv[r] = 1.0f / __shfl(lrun, lg * 4 + r);
#pragma unroll
        for (int r = 0; r < 4; ++r) {
            const size_t rowoff = ((size_t)(b * SEQ + qbase + lg * 4 + r)) * DM + h * DH;
            o[rowoff + 0 * 16 + lm] = f2b(o0[r] * linv[r]);
            o[rowoff + 1 * 16 + lm] = f2b(o1[r] * linv[r]);
            o[rowoff + 2 * 16 + lm] = f2b(o2[r] * linv[r]);
            o[rowoff + 3 * 16 + lm] = f2b(o3[r] * linv[r]);
        }
    }
}

// ---------------------------------------------------------------------------
extern "C" void kernel_launch(void* const* d_in, const int* in_sizes, int n_in,
                              void* d_out, int out_size, void* d_ws, size_t ws_size,
                              hipStream_t stream) {
    const float* x  = (const float*)d_in[0];
    const float* wq = (const float*)d_in[1];
    const float* wk = (const float*)d_in[2];
    const float* wv = (const float*)d_in[3];
    const float* wo = (const float*)d_in[4];
    float* out = (float*)d_out;

    const int TSZ = MROWS * DM;      // 4M
    const int WSZ = DM * DM;         // 1M
    char* ws = (char*)d_ws;
    const size_t MB = 1024 * 1024;
    unsigned short* xb      = (unsigned short*)(ws);             // 8 MB  (reused for attn_bf)
    unsigned short* wqkv    = (unsigned short*)(ws + 8 * MB);    // 6 MB
    unsigned short* wob     = (unsigned short*)(ws + 14 * MB);   // 2 MB
    unsigned short* qkv     = (unsigned short*)(ws + 16 * MB);   // 24 MB (interleaved q|k|v)
    unsigned short* vT      = (unsigned short*)(ws + 40 * MB);   // 8 MB
    unsigned short* attn_bf = xb;                                // xb dead after QKV GEMM

    cvt_f32_bf16<<<TSZ / 4 / 256, 256, 0, stream>>>(x, xb, TSZ);
    cvt3_f32_bf16<<<3 * WSZ / 4 / 256, 256, 0, stream>>>(wq, wk, wv, wqkv);
    cvt_f32_bf16<<<WSZ / 4 / 256, 256, 0, stream>>>(wo, wob, WSZ);

    // fused QKV GEMM: (4096 x 1024) x (3072 x 1024)^T -> qkv interleaved
    gemm_bt_mfma<true><<<dim3(DQKV / BN, MROWS / BM), 256, 0, stream>>>(xb, wqkv, qkv, MROWS, DQKV, DM);

    rope_qk_bf16<<<MROWS * 2, 256, 0, stream>>>(qkv);

    transpose_v<<<dim3(SEQ / 64, B_SZ * NH), 256, 0, stream>>>(qkv, vT);

    attn_mfma<<<512, 256, 0, stream>>>(qkv, vT, attn_bf);

    gemm_bt_mfma<false><<<dim3(DM / BN, MROWS / BM), 256, 0, stream>>>(attn_bf, wob, out, MROWS, DM, DM);
}

// Round 10
// 145.419 us; speedup vs baseline: 2.2086x; 1.4769x over previous
//
#include <hip/hip_runtime.h>
#include <math.h>

// Problem constants
#define B_SZ   2
#define SEQ    2048
#define DM     1024
#define NH     16
#define DH     64
#define MROWS  (B_SZ * SEQ)      // 4096
#define DQKV   (3 * DM)          // 3072, interleaved qkv row stride

typedef __attribute__((ext_vector_type(8))) short short8;
typedef __attribute__((ext_vector_type(4))) float f32x4;
typedef __attribute__((ext_vector_type(4))) unsigned short us4;
typedef __attribute__((ext_vector_type(2))) unsigned int u32x2;

__device__ __forceinline__ float b2f(unsigned short u) {
    union { float f; unsigned int i; } x; x.i = ((unsigned int)u) << 16; return x.f;
}
__device__ __forceinline__ unsigned short f2b(float f) {
    union { float f; unsigned int i; } x; x.f = f;
    return (unsigned short)((x.i + 0x7fffu + ((x.i >> 16) & 1u)) >> 16);
}

// async global->LDS, 16B per lane; lds base must be wave-uniform (HW adds lane*16)
__device__ __forceinline__ void gload_lds16(const unsigned short* g, unsigned short* lds_base_uniform) {
    __builtin_amdgcn_global_load_lds(
        (const __attribute__((address_space(1))) unsigned int*)g,
        (__attribute__((address_space(3))) unsigned int*)lds_base_uniform,
        16, 0, 0);
}

// ---------------------------------------------------------------------------
// f32 -> bf16 conversion (vectorized, n % 4 == 0)
// ---------------------------------------------------------------------------
__global__ __launch_bounds__(256) void cvt_f32_bf16(const float* __restrict__ in,
                                                    unsigned short* __restrict__ out, int n) {
    int i = blockIdx.x * blockDim.x + threadIdx.x;
    if (i * 4 >= n) return;
    float4 v = reinterpret_cast<const float4*>(in)[i];
    us4 o = { f2b(v.x), f2b(v.y), f2b(v.z), f2b(v.w) };
    reinterpret_cast<us4*>(out)[i] = o;
}

// 3 weights -> one concatenated bf16 buffer [3*DM][DM]
__global__ __launch_bounds__(256) void cvt3_f32_bf16(const float* __restrict__ a,
                                                     const float* __restrict__ b,
                                                     const float* __restrict__ c,
                                                     unsigned short* __restrict__ out) {
    const int each4 = DM * DM / 4;               // vec4 count per weight
    int i = blockIdx.x * blockDim.x + threadIdx.x;   // [0, 3*each4)
    const float* src = (i < each4) ? a : (i < 2 * each4) ? b : c;
    int off = (i < each4) ? i : (i < 2 * each4) ? i - each4 : i - 2 * each4;
    float4 v = reinterpret_cast<const float4*>(src)[off];
    us4 o = { f2b(v.x), f2b(v.y), f2b(v.z), f2b(v.w) };
    reinterpret_cast<us4*>(out)[i] = o;
}

// ---------------------------------------------------------------------------
// bf16 MFMA GEMM (m97 structure, single-buffered), 128x128 tile, BK=32.
// ---------------------------------------------------------------------------
#define BM 128
#define BN 128
#define BK 32

template <bool BF16OUT>
__global__ __launch_bounds__(256) void gemm_bt_mfma(const unsigned short* __restrict__ A,
                                                    const unsigned short* __restrict__ B,
                                                    void* __restrict__ Cout,
                                                    int M, int N, int K) {
    __shared__ unsigned short As[BM * BK];   // 8 KB
    __shared__ unsigned short Bs[BN * BK];   // 8 KB
    const int tid  = threadIdx.x;
    const int lane = tid & 63, wid = tid >> 6;
    const int wr = wid >> 1, wc = wid & 1;
    const int lm = lane & 15, lg = lane >> 4;
    const int brow = blockIdx.y * BM, bcol = blockIdx.x * BN;

    f32x4 acc[4][4] = {};

    const int rA  = tid >> 2;
    const int kc8 = (tid & 3) * 8;
    const unsigned short* gA0 = A + (size_t)(brow + rA) * K + kc8;
    const unsigned short* gA1 = A + (size_t)(brow + 64 + rA) * K + kc8;
    const unsigned short* gB0 = B + (size_t)(bcol + rA) * K + kc8;
    const unsigned short* gB1 = B + (size_t)(bcol + 64 + rA) * K + kc8;
    unsigned short* lA0 = As + wid * 512;
    unsigned short* lA1 = As + 2048 + wid * 512;
    unsigned short* lB0 = Bs + wid * 512;
    unsigned short* lB1 = Bs + 2048 + wid * 512;

    for (int k0 = 0; k0 < K; k0 += BK) {
        gload_lds16(gA0 + k0, lA0);
        gload_lds16(gA1 + k0, lA1);
        gload_lds16(gB0 + k0, lB0);
        gload_lds16(gB1 + k0, lB1);
        __syncthreads();

        short8 a[4], b[4];
#pragma unroll
        for (int m = 0; m < 4; ++m)
            a[m] = *reinterpret_cast<const short8*>(&As[(wr * 64 + m * 16 + lm) * BK + lg * 8]);
#pragma unroll
        for (int n = 0; n < 4; ++n)
            b[n] = *reinterpret_cast<const short8*>(&Bs[(wc * 64 + n * 16 + lm) * BK + lg * 8]);
#pragma unroll
        for (int m = 0; m < 4; ++m)
#pragma unroll
            for (int n = 0; n < 4; ++n)
                acc[m][n] = __builtin_amdgcn_mfma_f32_16x16x32_bf16(a[m], b[n], acc[m][n], 0, 0, 0);
        __syncthreads();
    }

#pragma unroll
    for (int m = 0; m < 4; ++m) {
#pragma unroll
        for (int r = 0; r < 4; ++r) {
            const size_t base = (size_t)(brow + wr * 64 + m * 16 + lg * 4 + r) * N + bcol + wc * 64 + lm;
#pragma unroll
            for (int n = 0; n < 4; ++n) {
                if (BF16OUT)
                    ((unsigned short*)Cout)[base + n * 16] = f2b(acc[m][n][r]);
                else
                    ((float*)Cout)[base + n * 16] = acc[m][n][r];
            }
        }
    }
}

// ---------------------------------------------------------------------------
// RoPE in place on interleaved qkv (q at col 0.., k at col 1024..).
// One s per block; 32 cos/sin computed into LDS. q scaled by log2(e)/8.
// ---------------------------------------------------------------------------
__global__ __launch_bounds__(256) void rope_qk_bf16(unsigned short* __restrict__ qkv) {
    __shared__ float cs_c[32], cs_s[32];
    const int tid = threadIdx.x;
    const int row = blockIdx.x >> 1;              // [0, MROWS)
    const int s   = row & (SEQ - 1);
    if (tid < 32) {
        float inv = powf(10000.0f, -(float)tid / 32.0f);
        float ang = (float)s * inv;
        cs_c[tid] = cosf(ang);
        cs_s[tid] = sinf(ang);
    }
    __syncthreads();
    const int idx = blockIdx.x * 256 + tid;
    const int i = idx & 31;
    const int h = (idx >> 5) & 15;
    const float c = cs_c[i], sn = cs_s[i];
    const size_t off = (size_t)row * DQKV + h * 64 + 2 * i;
    const float scale = 0.125f * 1.4426950408889634f;   // 1/sqrt(64) * log2(e)
    float qe = b2f(qkv[off]), qo = b2f(qkv[off + 1]);
    qkv[off]     = f2b((qe * c - qo * sn) * scale);
    qkv[off + 1] = f2b((qe * sn + qo * c) * scale);
    float ke = b2f(qkv[off + DM]), ko = b2f(qkv[off + DM + 1]);
    qkv[off + DM]     = f2b(ke * c - ko * sn);
    qkv[off + DM + 1] = f2b(ke * sn + ko * c);
}

// ---------------------------------------------------------------------------
// Transpose V (qkv cols 2048..3071): -> vT[(b*NH+h)*DH + d][s]   (bf16)
// ---------------------------------------------------------------------------
__global__ __launch_bounds__(256) void transpose_v(const unsigned short* __restrict__ qkv,
                                                   unsigned short* __restrict__ vT) {
    __shared__ unsigned short t[64][68];
    const int s0 = blockIdx.x * 64;
    const int bh = blockIdx.y;
    const int b = bh >> 4, h = bh & 15;
    const int tid = threadIdx.x;
    for (int idx = tid; idx < 1024; idx += 256) {
        int s = idx >> 4;
        int dg = (idx & 15) * 4;
        us4 val = *reinterpret_cast<const us4*>(qkv + (size_t)(b * SEQ + s0 + s) * DQKV + 2 * DM + h * DH + dg);
        *reinterpret_cast<us4*>(&t[s][dg]) = val;
    }
    __syncthreads();
    for (int idx = tid; idx < 1024; idx += 256) {
        int d = idx >> 4;
        int sg = (idx & 15) * 4;
        us4 val;
        val.x = t[sg + 0][d];
        val.y = t[sg + 1][d];
        val.z = t[sg + 2][d];
        val.w = t[sg + 3][d];
        *reinterpret_cast<us4*>(vT + (size_t)(bh * DH + d) * SEQ + s0 + sg) = val;
    }
}

// ---------------------------------------------------------------------------
// MFMA flash attention v8: block-shared LDS K/V staging.
// Block owns a 64-query chunk; wave w = rows chunk*64 + w*16. All 4 waves
// have IDENTICAL trip count nb = chunk+1 (16w+79 < 128) -> aligned barriers.
// Per iter: K(8KB)+V(8KB) staged once per block via global_load_lds
// (double-buffered), waves read ds_read_b128. XOR swizzle both-sides
// (rule #21): linear LDS dest + pre-swizzled global source
// (content slot = (tid&7)^(row&7)) + swizzled read addresses.
// Block pairing (chunks 31-c then c) -> every block exactly 33 iterations.
// XCD swizzle: bh & 7 == bid & 7 (4 bh per XCD, K/V L2-resident).
// Swapped QK^T -> in-register softmax + defer-max + setprio (unchanged).
// ---------------------------------------------------------------------------
__global__ __launch_bounds__(256, 2) void attn_mfma(const unsigned short* __restrict__ qkv,
                                                    const unsigned short* __restrict__ vT,
                                                    unsigned short* __restrict__ o) {
    const int tid  = threadIdx.x;
    const int wid  = tid >> 6;
    const int lane = tid & 63;
    const int lm = lane & 15, lg = lane >> 4;

    const int bid = blockIdx.x;             // [0,512)
    const int u   = bid >> 3;               // [0,64)
    const int bh  = (bid & 7) + 8 * (u >> 4);
    const int c0  = u & 15;                 // chunk-pair index
    const int b = bh >> 4, h = bh & 15;

    __shared__ unsigned short Kl[2][4096];     // 16 KB: 64 keys x 64 dims, swizzled
    __shared__ unsigned short Vl[2][4096];     // 16 KB: 64 dims x 64 keys, swizzled
    __shared__ unsigned int   Pex[4][16 * 34]; // 8.5 KB per-wave P exchange
    unsigned int* PW = Pex[wid];

    const unsigned short* kb = qkv + ((size_t)b * SEQ) * DQKV + DM + h * DH;
    const unsigned short* vb = vT + ((size_t)bh) * DH * SEQ;

    // staging: thread tid fills stored slot (tid&7) of row rloc (+32 round 2);
    // content slot for swizzle: cs = (tid&7) ^ (rloc&7)
    const int rloc = tid >> 3;               // 0..31
    const int cs   = (tid & 7) ^ (rloc & 7);
    const unsigned short* kst0 = kb + (size_t)rloc * DQKV + cs * 8;
    const unsigned short* kst1 = kb + (size_t)(rloc + 32) * DQKV + cs * 8;
    const unsigned short* vst0 = vb + (size_t)rloc * SEQ + cs * 8;
    const unsigned short* vst1 = vb + (size_t)(rloc + 32) * SEQ + cs * 8;
    const int sdst = wid * 512;              // this wave's 1KB (in shorts)

    // read-side swizzled 16B-slot offsets within a 128B row
    const int sl0  = (lg ^ (lm & 7)) << 4;
    const int sl1  = ((lg + 4) ^ (lm & 7)) << 4;
    const int rowb = lm * 128;               // + st*2048 per 16-row subtile

    const int wr_base = lm * 34 + lg * 2;                       // + st*8
    const int rd1 = lm * 34 + (lg >> 1) * 8 + (lg & 1) * 4;     // PV1 dwords
    const int rd2 = rd1 + 16;                                    // PV2

    for (int half = 0; half < 2; ++half) {
        const int c     = (half == 0) ? (31 - c0) : c0;
        const int qbase = c * 64 + wid * 16;
        const int nb    = c + 1;

        const unsigned short* qrow = qkv + ((size_t)(b * SEQ + qbase + lm)) * DQKV + h * DH;
        short8 qa0 = *reinterpret_cast<const short8*>(qrow + lg * 8);
        short8 qa1 = *reinterpret_cast<const short8*>(qrow + 32 + lg * 8);

        f32x4 o0 = {0.f, 0.f, 0.f, 0.f}, o1 = o0, o2 = o0, o3 = o0;
        float mrun = -INFINITY, lrun = 0.f;

        // prologue: stage tile 0 into buf 0
        gload_lds16(kst0, &Kl[0][sdst]);
        gload_lds16(kst1, &Kl[0][2048 + sdst]);
        gload_lds16(vst0, &Vl[0][sdst]);
        gload_lds16(vst1, &Vl[0][2048 + sdst]);
        __syncthreads();

        int buf = 0;
        for (int blk = 0; blk < nb; ++blk) {
            const int kbase = blk << 6;

            // prefetch next tile into buf^1 (drained by this iter's barrier)
            if (blk + 1 < nb) {
                const size_t ko = (size_t)(kbase + 64) * DQKV;
                const int    vo = kbase + 64;
                gload_lds16(kst0 + ko, &Kl[buf ^ 1][sdst]);
                gload_lds16(kst1 + ko, &Kl[buf ^ 1][2048 + sdst]);
                gload_lds16(vst0 + vo, &Vl[buf ^ 1][sdst]);
                gload_lds16(vst1 + vo, &Vl[buf ^ 1][2048 + sdst]);
            }

            const char* Kb = (const char*)&Kl[buf][0];
            const char* Vb = (const char*)&Vl[buf][0];

            // QK^T swapped: S^T[k][q] from LDS
            float s[16];
            __builtin_amdgcn_s_setprio(1);
#pragma unroll
            for (int st = 0; st < 4; ++st) {
                short8 k0 = *reinterpret_cast<const short8*>(Kb + st * 2048 + rowb + sl0);
                short8 k1 = *reinterpret_cast<const short8*>(Kb + st * 2048 + rowb + sl1);
                f32x4 t = {0.f, 0.f, 0.f, 0.f};
                t = __builtin_amdgcn_mfma_f32_16x16x32_bf16(k0, qa0, t, 0, 0, 0);
                t = __builtin_amdgcn_mfma_f32_16x16x32_bf16(k1, qa1, t, 0, 0, 0);
#pragma unroll
                for (int r = 0; r < 4; ++r) s[st * 4 + r] = t[r];
            }
            __builtin_amdgcn_s_setprio(0);

            // V fragments (LDS, independent of softmax -> scheduler can hoist)
            short8 vf[8];
#pragma unroll
            for (int c4 = 0; c4 < 4; ++c4) {
                vf[c4 * 2]     = *reinterpret_cast<const short8*>(Vb + c4 * 2048 + rowb + sl0);
                vf[c4 * 2 + 1] = *reinterpret_cast<const short8*>(Vb + c4 * 2048 + rowb + sl1);
            }

            // causal mask (last block only crosses the diagonal)
            if (blk == nb - 1) {
#pragma unroll
                for (int st = 0; st < 4; ++st)
#pragma unroll
                    for (int r = 0; r < 4; ++r) {
                        int kk = kbase + st * 16 + lg * 4 + r;
                        s[st * 4 + r] = (kk <= qbase + lm) ? s[st * 4 + r] : -INFINITY;
                    }
            }

            // in-lane max over this lane's 16 scores
            float t0 = fmaxf(s[0], s[1]),  t1 = fmaxf(s[2], s[3]);
            float t2 = fmaxf(s[4], s[5]),  t3 = fmaxf(s[6], s[7]);
            float t4 = fmaxf(s[8], s[9]),  t5 = fmaxf(s[10], s[11]);
            float t6 = fmaxf(s[12], s[13]), t7 = fmaxf(s[14], s[15]);
            float lmax = fmaxf(fmaxf(fmaxf(t0, t1), fmaxf(t2, t3)),
                               fmaxf(fmaxf(t4, t5), fmaxf(t6, t7)));

            // defer-max: cross-lane reduce + rescale only when needed
            if (!__all(lmax - mrun <= 8.0f)) {
                float mx = lmax;
                mx = fmaxf(mx, __shfl_xor(mx, 16));
                mx = fmaxf(mx, __shfl_xor(mx, 32));
                float mn  = fmaxf(mrun, mx);
                float fsc = exp2f(mrun - mn);
                mrun = mn;
                lrun *= fsc;
                float fr[4];
#pragma unroll
                for (int r = 0; r < 4; ++r) fr[r] = __shfl(fsc, lg * 4 + r);
#pragma unroll
                for (int r = 0; r < 4; ++r) {
                    o0[r] *= fr[r]; o1[r] *= fr[r]; o2[r] *= fr[r]; o3[r] *= fr[r];
                }
            }

            // P = exp2(S - mrun); sum feeds only lrun (off critical path)
#pragma unroll
            for (int i = 0; i < 16; ++i) s[i] = exp2f(s[i] - mrun);
            float a0 = (s[0] + s[1]) + (s[2] + s[3]);
            float a1 = (s[4] + s[5]) + (s[6] + s[7]);
            float a2 = (s[8] + s[9]) + (s[10] + s[11]);
            float a3 = (s[12] + s[13]) + (s[14] + s[15]);
            float ps = (a0 + a1) + (a2 + a3);
            ps += __shfl_xor(ps, 16);
            ps += __shfl_xor(ps, 32);
            lrun += ps;

            // pack P (round-to-nearest bf16) and relayout through LDS
#pragma unroll
            for (int st = 0; st < 4; ++st) {
                union { float f; unsigned int u; } e0, e1, e2, e3;
                e0.f = s[st * 4 + 0]; e1.f = s[st * 4 + 1];
                e2.f = s[st * 4 + 2]; e3.f = s[st * 4 + 3];
                u32x2 w;
                w.x = ((e0.u + 0x8000u) >> 16) | ((e1.u + 0x8000u) & 0xFFFF0000u);
                w.y = ((e2.u + 0x8000u) >> 16) | ((e3.u + 0x8000u) & 0xFFFF0000u);
                *reinterpret_cast<u32x2*>(&PW[wr_base + st * 8]) = w;
            }
            __builtin_amdgcn_wave_barrier();
            asm volatile("" ::: "memory");

            union { unsigned int u[4]; short8 v; } pk1, pk2;
            {
                u32x2 x0 = *reinterpret_cast<const u32x2*>(&PW[rd1]);
                u32x2 x1 = *reinterpret_cast<const u32x2*>(&PW[rd1 + 2]);
                pk1.u[0] = x0.x; pk1.u[1] = x0.y; pk1.u[2] = x1.x; pk1.u[3] = x1.y;
                u32x2 y0 = *reinterpret_cast<const u32x2*>(&PW[rd2]);
                u32x2 y1 = *reinterpret_cast<const u32x2*>(&PW[rd2 + 2]);
                pk2.u[0] = y0.x; pk2.u[1] = y0.y; pk2.u[2] = y1.x; pk2.u[3] = y1.y;
            }
            __builtin_amdgcn_wave_barrier();
            asm volatile("" ::: "memory");

            // PV: O[q = lg*4+r][d = lm + 16c]
            __builtin_amdgcn_s_setprio(1);
            o0 = __builtin_amdgcn_mfma_f32_16x16x32_bf16(pk1.v, vf[0], o0, 0, 0, 0);
            o0 = __builtin_amdgcn_mfma_f32_16x16x32_bf16(pk2.v, vf[1], o0, 0, 0, 0);
            o1 = __builtin_amdgcn_mfma_f32_16x16x32_bf16(pk1.v, vf[2], o1, 0, 0, 0);
            o1 = __builtin_amdgcn_mfma_f32_16x16x32_bf16(pk2.v, vf[3], o1, 0, 0, 0);
            o2 = __builtin_amdgcn_mfma_f32_16x16x32_bf16(pk1.v, vf[4], o2, 0, 0, 0);
            o2 = __builtin_amdgcn_mfma_f32_16x16x32_bf16(pk2.v, vf[5], o2, 0, 0, 0);
            o3 = __builtin_amdgcn_mfma_f32_16x16x32_bf16(pk1.v, vf[6], o3, 0, 0, 0);
            o3 = __builtin_amdgcn_mfma_f32_16x16x32_bf16(pk2.v, vf[7], o3, 0, 0, 0);
            __builtin_amdgcn_s_setprio(0);

            __syncthreads();   // drains this wave's prefetch; buf^1 ready
            buf ^= 1;
        }

        // epilogue: fetch l for output rows, normalize, store bf16
        float linv[4];
#pragma unroll
        for (int r = 0; r < 4; ++r) linv[r] = 1.0f / __shfl(lrun, lg * 4 + r);
#pragma unroll
        for (int r = 0; r < 4; ++r) {
            const size_t rowoff = ((size_t)(b * SEQ + qbase + lg * 4 + r)) * DM + h * DH;
            o[rowoff + 0 * 16 + lm] = f2b(o0[r] * linv[r]);
            o[rowoff + 1 * 16 + lm] = f2b(o1[r] * linv[r]);
            o[rowoff + 2 * 16 + lm] = f2b(o2[r] * linv[r]);
            o[rowoff + 3 * 16 + lm] = f2b(o3[r] * linv[r]);
        }
    }
}

// ---------------------------------------------------------------------------
extern "C" void kernel_launch(void* const* d_in, const int* in_sizes, int n_in,
                              void* d_out, int out_size, void* d_ws, size_t ws_size,
                              hipStream_t stream) {
    const float* x  = (const float*)d_in[0];
    const float* wq = (const float*)d_in[1];
    const float* wk = (const float*)d_in[2];
    const float* wv = (const float*)d_in[3];
    const float* wo = (const float*)d_in[4];
    float* out = (float*)d_out;

    const int TSZ = MROWS * DM;      // 4M
    const int WSZ = DM * DM;         // 1M
    char* ws = (char*)d_ws;
    const size_t MB = 1024 * 1024;
    unsigned short* xb      = (unsigned short*)(ws);             // 8 MB  (reused for attn_bf)
    unsigned short* wqkv    = (unsigned short*)(ws + 8 * MB);    // 6 MB
    unsigned short* wob     = (unsigned short*)(ws + 14 * MB);   // 2 MB
    unsigned short* qkv     = (unsigned short*)(ws + 16 * MB);   // 24 MB (interleaved q|k|v)
    unsigned short* vT      = (unsigned short*)(ws + 40 * MB);   // 8 MB
    unsigned short* attn_bf = xb;                                // xb dead after QKV GEMM

    cvt_f32_bf16<<<TSZ / 4 / 256, 256, 0, stream>>>(x, xb, TSZ);
    cvt3_f32_bf16<<<3 * WSZ / 4 / 256, 256, 0, stream>>>(wq, wk, wv, wqkv);
    cvt_f32_bf16<<<WSZ / 4 / 256, 256, 0, stream>>>(wo, wob, WSZ);

    // fused QKV GEMM: (4096 x 1024) x (3072 x 1024)^T -> qkv interleaved
    gemm_bt_mfma<true><<<dim3(DQKV / BN, MROWS / BM), 256, 0, stream>>>(xb, wqkv, qkv, MROWS, DQKV, DM);

    rope_qk_bf16<<<MROWS * 2, 256, 0, stream>>>(qkv);

    transpose_v<<<dim3(SEQ / 64, B_SZ * NH), 256, 0, stream>>>(qkv, vT);

    attn_mfma<<<512, 256, 0, stream>>>(qkv, vT, attn_bf);

    gemm_bt_mfma<false><<<dim3(DM / BN, MROWS / BM), 256, 0, stream>>>(attn_bf, wob, out, MROWS, DM, DM);
}

// Round 11
// 143.359 us; speedup vs baseline: 2.2404x; 1.0144x over previous
//
#include <hip/hip_runtime.h>
#include <hip/hip_bf16.h>
#include <math.h>

// Problem constants
#define B_SZ   2
#define SEQ    2048
#define DM     1024
#define NH     16
#define DH     64
#define MROWS  (B_SZ * SEQ)      // 4096
#define DQKV   (3 * DM)          // 3072, interleaved qkv row stride

typedef __attribute__((ext_vector_type(8))) short short8;
typedef __attribute__((ext_vector_type(4))) float f32x4;
typedef __attribute__((ext_vector_type(4))) unsigned short us4;
typedef __attribute__((ext_vector_type(2))) unsigned int u32x2;

__device__ __forceinline__ float b2f(unsigned short u) {
    union { float f; unsigned int i; } x; x.i = ((unsigned int)u) << 16; return x.f;
}
__device__ __forceinline__ unsigned short f2b(float f) {
    union { float f; unsigned int i; } x; x.f = f;
    return (unsigned short)((x.i + 0x7fffu + ((x.i >> 16) & 1u)) >> 16);
}
// packed f32x2 -> bf16x2 (compiler emits v_cvt_pk_bf16_f32)
__device__ __forceinline__ unsigned int pk2b(float a, float b) {
    float2 f2; f2.x = a; f2.y = b;
    __hip_bfloat162 hb = __float22bfloat162_rn(f2);
    return *reinterpret_cast<unsigned int*>(&hb);
}

// async global->LDS, 16B per lane; lds base must be wave-uniform (HW adds lane*16)
__device__ __forceinline__ void gload_lds16(const unsigned short* g, unsigned short* lds_base_uniform) {
    __builtin_amdgcn_global_load_lds(
        (const __attribute__((address_space(1))) unsigned int*)g,
        (__attribute__((address_space(3))) unsigned int*)lds_base_uniform,
        16, 0, 0);
}

// ---------------------------------------------------------------------------
// One-shot prep: x -> bf16, 4 weights -> bf16 (wq|wk|wv concat + wo),
// and the RoPE cos/sin table tab[s*32+i] = {cos,sin}(s * 10000^(-i/32)).
// ---------------------------------------------------------------------------
#define NX4 (MROWS * DM / 4)     // 2^20 vec4
#define NW4 (DM * DM / 4)        // 2^18 vec4

__global__ __launch_bounds__(256) void cvt_all(const float* __restrict__ x,
                                               const float* __restrict__ wq,
                                               const float* __restrict__ wk,
                                               const float* __restrict__ wv,
                                               const float* __restrict__ wo,
                                               unsigned short* __restrict__ xb,
                                               unsigned short* __restrict__ wqkv,
                                               unsigned short* __restrict__ wob,
                                               float* __restrict__ tab) {
    const int i = blockIdx.x * 256 + threadIdx.x;
    const int ncvt = NX4 + 4 * NW4;
    if (i < ncvt) {
        const float* src; unsigned short* dst; int off;
        if (i < NX4) { src = x; dst = xb; off = i; }
        else {
            int j = i - NX4;
            int w = j >> 18;
            off = j & (NW4 - 1);
            src = (w == 0) ? wq : (w == 1) ? wk : (w == 2) ? wv : wo;
            dst = (w < 3) ? wqkv + (size_t)w * DM * DM : wob;
        }
        float4 v = reinterpret_cast<const float4*>(src)[off];
        us4 o = { f2b(v.x), f2b(v.y), f2b(v.z), f2b(v.w) };
        reinterpret_cast<us4*>(dst)[off] = o;
    } else {
        int t = i - ncvt;               // [0, SEQ*32)
        if (t < SEQ * 32) {
            int s = t >> 5, fi = t & 31;
            float inv = powf(10000.0f, -(float)fi / 32.0f);
            float ang = (float)s * inv;
            tab[2 * t]     = cosf(ang);
            tab[2 * t + 1] = sinf(ang);
        }
    }
}

// ---------------------------------------------------------------------------
// bf16 MFMA GEMM (m97 structure), 128x128 tile, BK=32.  C = A(M,K) * B(N,K)^T
// ---------------------------------------------------------------------------
#define BM 128
#define BN 128
#define BK 32

template <bool BF16OUT>
__global__ __launch_bounds__(256) void gemm_bt_mfma(const unsigned short* __restrict__ A,
                                                    const unsigned short* __restrict__ B,
                                                    void* __restrict__ Cout,
                                                    int M, int N, int K) {
    __shared__ unsigned short As[BM * BK];   // 8 KB
    __shared__ unsigned short Bs[BN * BK];   // 8 KB
    const int tid  = threadIdx.x;
    const int lane = tid & 63, wid = tid >> 6;
    const int wr = wid >> 1, wc = wid & 1;
    const int lm = lane & 15, lg = lane >> 4;
    const int brow = blockIdx.y * BM, bcol = blockIdx.x * BN;

    f32x4 acc[4][4] = {};

    const int rA  = tid >> 2;
    const int kc8 = (tid & 3) * 8;
    const unsigned short* gA0 = A + (size_t)(brow + rA) * K + kc8;
    const unsigned short* gA1 = A + (size_t)(brow + 64 + rA) * K + kc8;
    const unsigned short* gB0 = B + (size_t)(bcol + rA) * K + kc8;
    const unsigned short* gB1 = B + (size_t)(bcol + 64 + rA) * K + kc8;
    unsigned short* lA0 = As + wid * 512;
    unsigned short* lA1 = As + 2048 + wid * 512;
    unsigned short* lB0 = Bs + wid * 512;
    unsigned short* lB1 = Bs + 2048 + wid * 512;

    for (int k0 = 0; k0 < K; k0 += BK) {
        gload_lds16(gA0 + k0, lA0);
        gload_lds16(gA1 + k0, lA1);
        gload_lds16(gB0 + k0, lB0);
        gload_lds16(gB1 + k0, lB1);
        __syncthreads();

        short8 a[4], b[4];
#pragma unroll
        for (int m = 0; m < 4; ++m)
            a[m] = *reinterpret_cast<const short8*>(&As[(wr * 64 + m * 16 + lm) * BK + lg * 8]);
#pragma unroll
        for (int n = 0; n < 4; ++n)
            b[n] = *reinterpret_cast<const short8*>(&Bs[(wc * 64 + n * 16 + lm) * BK + lg * 8]);
#pragma unroll
        for (int m = 0; m < 4; ++m)
#pragma unroll
            for (int n = 0; n < 4; ++n)
                acc[m][n] = __builtin_amdgcn_mfma_f32_16x16x32_bf16(a[m], b[n], acc[m][n], 0, 0, 0);
        __syncthreads();
    }

#pragma unroll
    for (int m = 0; m < 4; ++m) {
#pragma unroll
        for (int r = 0; r < 4; ++r) {
            const size_t base = (size_t)(brow + wr * 64 + m * 16 + lg * 4 + r) * N + bcol + wc * 64 + lm;
#pragma unroll
            for (int n = 0; n < 4; ++n) {
                if (BF16OUT)
                    ((unsigned short*)Cout)[base + n * 16] = f2b(acc[m][n][r]);
                else
                    ((float*)Cout)[base + n * 16] = acc[m][n][r];
            }
        }
    }
}

// ---------------------------------------------------------------------------
// QKV GEMM with fused RoPE (q/k) and transposed V write.
// A = xb (M=4096, K=1024), B = wqkv (N=3072, K=1024).
// col-tiles 0..7 -> q (rope, scaled log2e/8), 8..15 -> k (rope),
// 16..23 -> v (write to vT[(b*NH+h)*DH+d][s], 8B per (m,n) via r-regs).
// ---------------------------------------------------------------------------
__global__ __launch_bounds__(256) void gemm_qkv(const unsigned short* __restrict__ A,
                                                const unsigned short* __restrict__ B,
                                                unsigned short* __restrict__ qkv,
                                                unsigned short* __restrict__ vT,
                                                const float* __restrict__ tab) {
    __shared__ unsigned short As[BM * BK];
    __shared__ unsigned short Bs[BN * BK];
    const int tid  = threadIdx.x;
    const int lane = tid & 63, wid = tid >> 6;
    const int wr = wid >> 1, wc = wid & 1;
    const int lm = lane & 15, lg = lane >> 4;
    const int brow = blockIdx.y * BM, bcol = blockIdx.x * BN;
    const int K = DM;

    f32x4 acc[4][4] = {};

    const int rA  = tid >> 2;
    const int kc8 = (tid & 3) * 8;
    const unsigned short* gA0 = A + (size_t)(brow + rA) * K + kc8;
    const unsigned short* gA1 = A + (size_t)(brow + 64 + rA) * K + kc8;
    const unsigned short* gB0 = B + (size_t)(bcol + rA) * K + kc8;
    const unsigned short* gB1 = B + (size_t)(bcol + 64 + rA) * K + kc8;
    unsigned short* lA0 = As + wid * 512;
    unsigned short* lA1 = As + 2048 + wid * 512;
    unsigned short* lB0 = Bs + wid * 512;
    unsigned short* lB1 = Bs + 2048 + wid * 512;

    for (int k0 = 0; k0 < K; k0 += BK) {
        gload_lds16(gA0 + k0, lA0);
        gload_lds16(gA1 + k0, lA1);
        gload_lds16(gB0 + k0, lB0);
        gload_lds16(gB1 + k0, lB1);
        __syncthreads();

        short8 a[4], b[4];
#pragma unroll
        for (int m = 0; m < 4; ++m)
            a[m] = *reinterpret_cast<const short8*>(&As[(wr * 64 + m * 16 + lm) * BK + lg * 8]);
#pragma unroll
        for (int n = 0; n < 4; ++n)
            b[n] = *reinterpret_cast<const short8*>(&Bs[(wc * 64 + n * 16 + lm) * BK + lg * 8]);
#pragma unroll
        for (int m = 0; m < 4; ++m)
#pragma unroll
            for (int n = 0; n < 4; ++n)
                acc[m][n] = __builtin_amdgcn_mfma_f32_16x16x32_bf16(a[m], b[n], acc[m][n], 0, 0, 0);
        __syncthreads();
    }

    const int reg = blockIdx.x >> 3;    // 0=q, 1=k, 2=v (uniform per block)
    if (reg < 2) {
        // rope: lane holds col c; partner c^1 lives in lane lm^1
        const float qs = (reg == 0) ? (0.125f * 1.4426950408889634f) : 1.0f;
        const int odd = lm & 1;
#pragma unroll
        for (int m = 0; m < 4; ++m) {
#pragma unroll
            for (int r = 0; r < 4; ++r) {
                const int row = brow + wr * 64 + m * 16 + lg * 4 + r;
                const int s   = row & (SEQ - 1);
                const size_t base = (size_t)row * DQKV + bcol + wc * 64 + lm;
#pragma unroll
                for (int n = 0; n < 4; ++n) {
                    float v  = acc[m][n][r];
                    float pv = __shfl_xor(v, 1);
                    const int fi = (n * 16 + lm) >> 1;
                    float2 cs = reinterpret_cast<const float2*>(tab)[s * 32 + fi];
                    float c = cs.x * qs, sn = cs.y * qs;
                    float out = odd ? (pv * sn + v * c) : (v * c - pv * sn);
                    qkv[base + n * 16] = f2b(out);
                }
            }
        }
    } else {
        // v: write transposed. acc[m][n][0..3] are 4 consecutive rows (s).
        const int b = brow >> 11;
#pragma unroll
        for (int m = 0; m < 4; ++m) {
            const int s0 = (brow + wr * 64 + m * 16 + lg * 4) & (SEQ - 1);
#pragma unroll
            for (int n = 0; n < 4; ++n) {
                const int vcol = bcol + wc * 64 + n * 16 + lm - 2 * DM;
                const int h = vcol >> 6, d = vcol & 63;
                us4 val = { f2b(acc[m][n][0]), f2b(acc[m][n][1]),
                            f2b(acc[m][n][2]), f2b(acc[m][n][3]) };
                *reinterpret_cast<us4*>(vT + (size_t)((b * NH + h) * DH + d) * SEQ + s0) = val;
            }
        }
    }
}

// ---------------------------------------------------------------------------
// MFMA flash attention v9 (= v8 + cvt_pk P-pack).
// Block-shared LDS K/V staging, double-buffered; 64-query chunk per block;
// chunk pairing (31-c, c) -> every block exactly 33 iterations.
// XCD swizzle: bh & 7 == bid & 7. Swapped QK^T -> in-register softmax,
// defer-max, setprio. Both-sides XOR swizzle on K/V staging (rule #21).
// ---------------------------------------------------------------------------
__global__ __launch_bounds__(256, 2) void attn_mfma(const unsigned short* __restrict__ qkv,
                                                    const unsigned short* __restrict__ vT,
                                                    unsigned short* __restrict__ o) {
    const int tid  = threadIdx.x;
    const int wid  = tid >> 6;
    const int lane = tid & 63;
    const int lm = lane & 15, lg = lane >> 4;

    const int bid = blockIdx.x;             // [0,512)
    const int u   = bid >> 3;               // [0,64)
    const int bh  = (bid & 7) + 8 * (u >> 4);
    const int c0  = u & 15;                 // chunk-pair index
    const int b = bh >> 4, h = bh & 15;

    __shared__ unsigned short Kl[2][4096];     // 16 KB
    __shared__ unsigned short Vl[2][4096];     // 16 KB
    __shared__ unsigned int   Pex[4][16 * 34]; // 8.5 KB
    unsigned int* PW = Pex[wid];

    const unsigned short* kb = qkv + ((size_t)b * SEQ) * DQKV + DM + h * DH;
    const unsigned short* vb = vT + ((size_t)bh) * DH * SEQ;

    const int rloc = tid >> 3;               // 0..31
    const int cs   = (tid & 7) ^ (rloc & 7);
    const unsigned short* kst0 = kb + (size_t)rloc * DQKV + cs * 8;
    const unsigned short* kst1 = kb + (size_t)(rloc + 32) * DQKV + cs * 8;
    const unsigned short* vst0 = vb + (size_t)rloc * SEQ + cs * 8;
    const unsigned short* vst1 = vb + (size_t)(rloc + 32) * SEQ + cs * 8;
    const int sdst = wid * 512;

    const int sl0  = (lg ^ (lm & 7)) << 4;
    const int sl1  = ((lg + 4) ^ (lm & 7)) << 4;
    const int rowb = lm * 128;

    const int wr_base = lm * 34 + lg * 2;
    const int rd1 = lm * 34 + (lg >> 1) * 8 + (lg & 1) * 4;
    const int rd2 = rd1 + 16;

    for (int half = 0; half < 2; ++half) {
        const int c     = (half == 0) ? (31 - c0) : c0;
        const int qbase = c * 64 + wid * 16;
        const int nb    = c + 1;

        const unsigned short* qrow = qkv + ((size_t)(b * SEQ + qbase + lm)) * DQKV + h * DH;
        short8 qa0 = *reinterpret_cast<const short8*>(qrow + lg * 8);
        short8 qa1 = *reinterpret_cast<const short8*>(qrow + 32 + lg * 8);

        f32x4 o0 = {0.f, 0.f, 0.f, 0.f}, o1 = o0, o2 = o0, o3 = o0;
        float mrun = -INFINITY, lrun = 0.f;

        gload_lds16(kst0, &Kl[0][sdst]);
        gload_lds16(kst1, &Kl[0][2048 + sdst]);
        gload_lds16(vst0, &Vl[0][sdst]);
        gload_lds16(vst1, &Vl[0][2048 + sdst]);
        __syncthreads();

        int buf = 0;
        for (int blk = 0; blk < nb; ++blk) {
            const int kbase = blk << 6;

            if (blk + 1 < nb) {
                const size_t ko = (size_t)(kbase + 64) * DQKV;
                const int    vo = kbase + 64;
                gload_lds16(kst0 + ko, &Kl[buf ^ 1][sdst]);
                gload_lds16(kst1 + ko, &Kl[buf ^ 1][2048 + sdst]);
                gload_lds16(vst0 + vo, &Vl[buf ^ 1][sdst]);
                gload_lds16(vst1 + vo, &Vl[buf ^ 1][2048 + sdst]);
            }

            const char* Kb = (const char*)&Kl[buf][0];
            const char* Vb = (const char*)&Vl[buf][0];

            float s[16];
            __builtin_amdgcn_s_setprio(1);
#pragma unroll
            for (int st = 0; st < 4; ++st) {
                short8 k0 = *reinterpret_cast<const short8*>(Kb + st * 2048 + rowb + sl0);
                short8 k1 = *reinterpret_cast<const short8*>(Kb + st * 2048 + rowb + sl1);
                f32x4 t = {0.f, 0.f, 0.f, 0.f};
                t = __builtin_amdgcn_mfma_f32_16x16x32_bf16(k0, qa0, t, 0, 0, 0);
                t = __builtin_amdgcn_mfma_f32_16x16x32_bf16(k1, qa1, t, 0, 0, 0);
#pragma unroll
                for (int r = 0; r < 4; ++r) s[st * 4 + r] = t[r];
            }
            __builtin_amdgcn_s_setprio(0);

            short8 vf[8];
#pragma unroll
            for (int c4 = 0; c4 < 4; ++c4) {
                vf[c4 * 2]     = *reinterpret_cast<const short8*>(Vb + c4 * 2048 + rowb + sl0);
                vf[c4 * 2 + 1] = *reinterpret_cast<const short8*>(Vb + c4 * 2048 + rowb + sl1);
            }

            if (blk == nb - 1) {
#pragma unroll
                for (int st = 0; st < 4; ++st)
#pragma unroll
                    for (int r = 0; r < 4; ++r) {
                        int kk = kbase + st * 16 + lg * 4 + r;
                        s[st * 4 + r] = (kk <= qbase + lm) ? s[st * 4 + r] : -INFINITY;
                    }
            }

            float t0 = fmaxf(s[0], s[1]),  t1 = fmaxf(s[2], s[3]);
            float t2 = fmaxf(s[4], s[5]),  t3 = fmaxf(s[6], s[7]);
            float t4 = fmaxf(s[8], s[9]),  t5 = fmaxf(s[10], s[11]);
            float t6 = fmaxf(s[12], s[13]), t7 = fmaxf(s[14], s[15]);
            float lmax = fmaxf(fmaxf(fmaxf(t0, t1), fmaxf(t2, t3)),
                               fmaxf(fmaxf(t4, t5), fmaxf(t6, t7)));

            if (!__all(lmax - mrun <= 8.0f)) {
                float mx = lmax;
                mx = fmaxf(mx, __shfl_xor(mx, 16));
                mx = fmaxf(mx, __shfl_xor(mx, 32));
                float mn  = fmaxf(mrun, mx);
                float fsc = exp2f(mrun - mn);
                mrun = mn;
                lrun *= fsc;
                float fr[4];
#pragma unroll
                for (int r = 0; r < 4; ++r) fr[r] = __shfl(fsc, lg * 4 + r);
#pragma unroll
                for (int r = 0; r < 4; ++r) {
                    o0[r] *= fr[r]; o1[r] *= fr[r]; o2[r] *= fr[r]; o3[r] *= fr[r];
                }
            }

#pragma unroll
            for (int i = 0; i < 16; ++i) s[i] = exp2f(s[i] - mrun);
            float a0 = (s[0] + s[1]) + (s[2] + s[3]);
            float a1 = (s[4] + s[5]) + (s[6] + s[7]);
            float a2 = (s[8] + s[9]) + (s[10] + s[11]);
            float a3 = (s[12] + s[13]) + (s[14] + s[15]);
            float ps = (a0 + a1) + (a2 + a3);
            ps += __shfl_xor(ps, 16);
            ps += __shfl_xor(ps, 32);
            lrun += ps;

            // pack P via v_cvt_pk_bf16_f32 and relayout through LDS
#pragma unroll
            for (int st = 0; st < 4; ++st) {
                u32x2 w;
                w.x = pk2b(s[st * 4 + 0], s[st * 4 + 1]);
                w.y = pk2b(s[st * 4 + 2], s[st * 4 + 3]);
                *reinterpret_cast<u32x2*>(&PW[wr_base + st * 8]) = w;
            }
            __builtin_amdgcn_wave_barrier();
            asm volatile("" ::: "memory");

            union { unsigned int u[4]; short8 v; } pk1, pk2;
            {
                u32x2 x0 = *reinterpret_cast<const u32x2*>(&PW[rd1]);
                u32x2 x1 = *reinterpret_cast<const u32x2*>(&PW[rd1 + 2]);
                pk1.u[0] = x0.x; pk1.u[1] = x0.y; pk1.u[2] = x1.x; pk1.u[3] = x1.y;
                u32x2 y0 = *reinterpret_cast<const u32x2*>(&PW[rd2]);
                u32x2 y1 = *reinterpret_cast<const u32x2*>(&PW[rd2 + 2]);
                pk2.u[0] = y0.x; pk2.u[1] = y0.y; pk2.u[2] = y1.x; pk2.u[3] = y1.y;
            }
            __builtin_amdgcn_wave_barrier();
            asm volatile("" ::: "memory");

            __builtin_amdgcn_s_setprio(1);
            o0 = __builtin_amdgcn_mfma_f32_16x16x32_bf16(pk1.v, vf[0], o0, 0, 0, 0);
            o0 = __builtin_amdgcn_mfma_f32_16x16x32_bf16(pk2.v, vf[1], o0, 0, 0, 0);
            o1 = __builtin_amdgcn_mfma_f32_16x16x32_bf16(pk1.v, vf[2], o1, 0, 0, 0);
            o1 = __builtin_amdgcn_mfma_f32_16x16x32_bf16(pk2.v, vf[3], o1, 0, 0, 0);
            o2 = __builtin_amdgcn_mfma_f32_16x16x32_bf16(pk1.v, vf[4], o2, 0, 0, 0);
            o2 = __builtin_amdgcn_mfma_f32_16x16x32_bf16(pk2.v, vf[5], o2, 0, 0, 0);
            o3 = __builtin_amdgcn_mfma_f32_16x16x32_bf16(pk1.v, vf[6], o3, 0, 0, 0);
            o3 = __builtin_amdgcn_mfma_f32_16x16x32_bf16(pk2.v, vf[7], o3, 0, 0, 0);
            __builtin_amdgcn_s_setprio(0);

            __syncthreads();
            buf ^= 1;
        }

        float linv[4];
#pragma unroll
        for (int r = 0; r < 4; ++r) linv[r] = 1.0f / __shfl(lrun, lg * 4 + r);
#pragma unroll
        for (int r = 0; r < 4; ++r) {
            const size_t rowoff = ((size_t)(b * SEQ + qbase + lg * 4 + r)) * DM + h * DH;
            o[rowoff + 0 * 16 + lm] = f2b(o0[r] * linv[r]);
            o[rowoff + 1 * 16 + lm] = f2b(o1[r] * linv[r]);
            o[rowoff + 2 * 16 + lm] = f2b(o2[r] * linv[r]);
            o[rowoff + 3 * 16 + lm] = f2b(o3[r] * linv[r]);
        }
    }
}

// ---------------------------------------------------------------------------
extern "C" void kernel_launch(void* const* d_in, const int* in_sizes, int n_in,
                              void* d_out, int out_size, void* d_ws, size_t ws_size,
                              hipStream_t stream) {
    const float* x  = (const float*)d_in[0];
    const float* wq = (const float*)d_in[1];
    const float* wk = (const float*)d_in[2];
    const float* wv = (const float*)d_in[3];
    const float* wo = (const float*)d_in[4];
    float* out = (float*)d_out;

    char* ws = (char*)d_ws;
    const size_t MB = 1024 * 1024;
    unsigned short* xb      = (unsigned short*)(ws);             // 8 MB  (reused for attn_bf)
    unsigned short* wqkv    = (unsigned short*)(ws + 8 * MB);    // 6 MB
    unsigned short* wob     = (unsigned short*)(ws + 14 * MB);   // 2 MB
    unsigned short* qkv     = (unsigned short*)(ws + 16 * MB);   // 24 MB (q|k roped; v region unused)
    unsigned short* vT      = (unsigned short*)(ws + 40 * MB);   // 8 MB
    float*          ropetab = (float*)(ws + 48 * MB);            // 512 KB
    unsigned short* attn_bf = xb;                                // xb dead after QKV GEMM

    // 1: all conversions + rope table
    const int cvt_grid = (NX4 + 4 * NW4 + SEQ * 32) / 256;
    cvt_all<<<cvt_grid, 256, 0, stream>>>(x, wq, wk, wv, wo, xb, wqkv, wob, ropetab);

    // 2: fused QKV GEMM + RoPE + V-transpose
    gemm_qkv<<<dim3(DQKV / BN, MROWS / BM), 256, 0, stream>>>(xb, wqkv, qkv, vT, ropetab);

    // 3: flash attention
    attn_mfma<<<512, 256, 0, stream>>>(qkv, vT, attn_bf);

    // 4: output projection
    gemm_bt_mfma<false><<<dim3(DM / BN, MROWS / BM), 256, 0, stream>>>(attn_bf, wob, out, MROWS, DM, DM);
}

// Round 12
// 126.122 us; speedup vs baseline: 2.5466x; 1.1367x over previous
//
#include <hip/hip_runtime.h>
#include <hip/hip_bf16.h>
#include <math.h>

// Problem constants
#define B_SZ   2
#define SEQ    2048
#define DM     1024
#define NH     16
#define DH     64
#define MROWS  (B_SZ * SEQ)      // 4096
#define DQKV   (3 * DM)          // 3072, interleaved qkv row stride

typedef __attribute__((ext_vector_type(8))) short short8;
typedef __attribute__((ext_vector_type(4))) float f32x4;
typedef __attribute__((ext_vector_type(4))) unsigned short us4;
typedef __attribute__((ext_vector_type(2))) unsigned int u32x2;

__device__ __forceinline__ float b2f(unsigned short u) {
    union { float f; unsigned int i; } x; x.i = ((unsigned int)u) << 16; return x.f;
}
__device__ __forceinline__ unsigned short f2b(float f) {
    union { float f; unsigned int i; } x; x.f = f;
    return (unsigned short)((x.i + 0x7fffu + ((x.i >> 16) & 1u)) >> 16);
}
// packed f32x2 -> bf16x2 (compiler emits v_cvt_pk_bf16_f32)
__device__ __forceinline__ unsigned int pk2b(float a, float b) {
    float2 f2; f2.x = a; f2.y = b;
    __hip_bfloat162 hb = __float22bfloat162_rn(f2);
    return *reinterpret_cast<unsigned int*>(&hb);
}

// async global->LDS, 16B per lane; lds base must be wave-uniform (HW adds lane*16)
__device__ __forceinline__ void gload_lds16(const unsigned short* g, unsigned short* lds_base_uniform) {
    __builtin_amdgcn_global_load_lds(
        (const __attribute__((address_space(1))) unsigned int*)g,
        (__attribute__((address_space(3))) unsigned int*)lds_base_uniform,
        16, 0, 0);
}

// ---------------------------------------------------------------------------
// One-shot prep: x -> bf16, 4 weights -> bf16 (wq|wk|wv concat + wo),
// and the RoPE cos/sin table tab[s*32+i] = {cos,sin}(s * 10000^(-i/32)).
// ---------------------------------------------------------------------------
#define NX4 (MROWS * DM / 4)     // 2^20 vec4
#define NW4 (DM * DM / 4)        // 2^18 vec4

__global__ __launch_bounds__(256) void cvt_all(const float* __restrict__ x,
                                               const float* __restrict__ wq,
                                               const float* __restrict__ wk,
                                               const float* __restrict__ wv,
                                               const float* __restrict__ wo,
                                               unsigned short* __restrict__ xb,
                                               unsigned short* __restrict__ wqkv,
                                               unsigned short* __restrict__ wob,
                                               float* __restrict__ tab) {
    const int i = blockIdx.x * 256 + threadIdx.x;
    const int ncvt = NX4 + 4 * NW4;
    if (i < ncvt) {
        const float* src; unsigned short* dst; int off;
        if (i < NX4) { src = x; dst = xb; off = i; }
        else {
            int j = i - NX4;
            int w = j >> 18;
            off = j & (NW4 - 1);
            src = (w == 0) ? wq : (w == 1) ? wk : (w == 2) ? wv : wo;
            dst = (w < 3) ? wqkv + (size_t)w * DM * DM : wob;
        }
        float4 v = reinterpret_cast<const float4*>(src)[off];
        us4 o = { f2b(v.x), f2b(v.y), f2b(v.z), f2b(v.w) };
        reinterpret_cast<us4*>(dst)[off] = o;
    } else {
        int t = i - ncvt;               // [0, SEQ*32)
        if (t < SEQ * 32) {
            int s = t >> 5, fi = t & 31;
            float inv = powf(10000.0f, -(float)fi / 32.0f);
            float ang = (float)s * inv;
            tab[2 * t]     = cosf(ang);
            tab[2 * t + 1] = sinf(ang);
        }
    }
}

// ---------------------------------------------------------------------------
// 2-phase double-buffered bf16 MFMA GEMM, 128x128 tile, BK=32, fp32 out.
// Loop: STAGE(buf^1, k+1) issued BEFORE compute(buf); ONE barrier per step
// (its vmcnt(0) drain lands after ~16 MFMAs -> latency hidden).
// ---------------------------------------------------------------------------
#define BM 128
#define BN 128
#define BK 32

__global__ __launch_bounds__(256, 2) void gemm_out(const unsigned short* __restrict__ A,
                                                   const unsigned short* __restrict__ B,
                                                   float* __restrict__ Cout) {
    // 128x64 tile, 4 waves stacked in M (each wave 32 rows x 64 cols)
    const int OBM = 128, OBN = 64;
    __shared__ unsigned short As[2][OBM * BK];   // 2 x 8 KB
    __shared__ unsigned short Bs[2][OBN * BK];   // 2 x 4 KB
    const int tid  = threadIdx.x;
    const int lane = tid & 63, wid = tid >> 6;
    const int lm = lane & 15, lg = lane >> 4;
    const int brow = blockIdx.y * OBM, bcol = blockIdx.x * OBN;
    const int K = DM, N = DM;

    f32x4 acc[2][4] = {};

    const int rA  = tid >> 2;
    const int kc8 = (tid & 3) * 8;
    const unsigned short* gA0 = A + (size_t)(brow + rA) * K + kc8;
    const unsigned short* gA1 = A + (size_t)(brow + 64 + rA) * K + kc8;
    const unsigned short* gB0 = B + (size_t)(bcol + rA) * K + kc8;
    unsigned short* lA0 = (unsigned short*)As + wid * 512;          // +buf*4096
    unsigned short* lA1 = (unsigned short*)As + 2048 + wid * 512;
    unsigned short* lB0 = (unsigned short*)Bs + wid * 512;          // +buf*2048

    // prologue: stage tile 0 into buf 0
    gload_lds16(gA0, lA0);
    gload_lds16(gA1, lA1);
    gload_lds16(gB0, lB0);
    __syncthreads();

    int buf = 0;
    for (int k0 = 0; k0 < K; k0 += BK) {
        if (k0 + BK < K) {
            gload_lds16(gA0 + k0 + BK, lA0 + (buf ^ 1) * 4096);
            gload_lds16(gA1 + k0 + BK, lA1 + (buf ^ 1) * 4096);
            gload_lds16(gB0 + k0 + BK, lB0 + (buf ^ 1) * 2048);
        }
        short8 a[2], b[4];
#pragma unroll
        for (int m = 0; m < 2; ++m)
            a[m] = *reinterpret_cast<const short8*>(&As[buf][(wid * 32 + m * 16 + lm) * BK + lg * 8]);
#pragma unroll
        for (int n = 0; n < 4; ++n)
            b[n] = *reinterpret_cast<const short8*>(&Bs[buf][(n * 16 + lm) * BK + lg * 8]);
#pragma unroll
        for (int m = 0; m < 2; ++m)
#pragma unroll
            for (int n = 0; n < 4; ++n)
                acc[m][n] = __builtin_amdgcn_mfma_f32_16x16x32_bf16(a[m], b[n], acc[m][n], 0, 0, 0);
        __syncthreads();
        buf ^= 1;
    }

#pragma unroll
    for (int m = 0; m < 2; ++m) {
#pragma unroll
        for (int r = 0; r < 4; ++r) {
            const size_t base = (size_t)(brow + wid * 32 + m * 16 + lg * 4 + r) * N + bcol + lm;
#pragma unroll
            for (int n = 0; n < 4; ++n)
                Cout[base + n * 16] = acc[m][n][r];
        }
    }
}

// ---------------------------------------------------------------------------
// QKV GEMM (2-phase dbuf) with fused RoPE (q/k) and transposed V write.
// col-tiles 0..7 -> q (rope, scaled log2e/8), 8..15 -> k (rope), 16..23 -> v.
// ---------------------------------------------------------------------------
__global__ __launch_bounds__(256, 2) void gemm_qkv(const unsigned short* __restrict__ A,
                                                   const unsigned short* __restrict__ B,
                                                   unsigned short* __restrict__ qkv,
                                                   unsigned short* __restrict__ vT,
                                                   const float* __restrict__ tab) {
    __shared__ unsigned short As[2][BM * BK];   // 2 x 8 KB
    __shared__ unsigned short Bs[2][BN * BK];   // 2 x 8 KB
    const int tid  = threadIdx.x;
    const int lane = tid & 63, wid = tid >> 6;
    const int wr = wid >> 1, wc = wid & 1;
    const int lm = lane & 15, lg = lane >> 4;
    const int brow = blockIdx.y * BM, bcol = blockIdx.x * BN;
    const int K = DM;

    f32x4 acc[4][4] = {};

    const int rA  = tid >> 2;
    const int kc8 = (tid & 3) * 8;
    const unsigned short* gA0 = A + (size_t)(brow + rA) * K + kc8;
    const unsigned short* gA1 = A + (size_t)(brow + 64 + rA) * K + kc8;
    const unsigned short* gB0 = B + (size_t)(bcol + rA) * K + kc8;
    const unsigned short* gB1 = B + (size_t)(bcol + 64 + rA) * K + kc8;
    unsigned short* lA0 = (unsigned short*)As + wid * 512;          // +buf*4096
    unsigned short* lA1 = (unsigned short*)As + 2048 + wid * 512;
    unsigned short* lB0 = (unsigned short*)Bs + wid * 512;
    unsigned short* lB1 = (unsigned short*)Bs + 2048 + wid * 512;

    gload_lds16(gA0, lA0);
    gload_lds16(gA1, lA1);
    gload_lds16(gB0, lB0);
    gload_lds16(gB1, lB1);
    __syncthreads();

    int buf = 0;
    for (int k0 = 0; k0 < K; k0 += BK) {
        if (k0 + BK < K) {
            const int bo = (buf ^ 1) * 4096;
            gload_lds16(gA0 + k0 + BK, lA0 + bo);
            gload_lds16(gA1 + k0 + BK, lA1 + bo);
            gload_lds16(gB0 + k0 + BK, lB0 + bo);
            gload_lds16(gB1 + k0 + BK, lB1 + bo);
        }
        short8 a[4], b[4];
#pragma unroll
        for (int m = 0; m < 4; ++m)
            a[m] = *reinterpret_cast<const short8*>(&As[buf][(wr * 64 + m * 16 + lm) * BK + lg * 8]);
#pragma unroll
        for (int n = 0; n < 4; ++n)
            b[n] = *reinterpret_cast<const short8*>(&Bs[buf][(wc * 64 + n * 16 + lm) * BK + lg * 8]);
#pragma unroll
        for (int m = 0; m < 4; ++m)
#pragma unroll
            for (int n = 0; n < 4; ++n)
                acc[m][n] = __builtin_amdgcn_mfma_f32_16x16x32_bf16(a[m], b[n], acc[m][n], 0, 0, 0);
        __syncthreads();
        buf ^= 1;
    }

    const int reg = blockIdx.x >> 3;    // 0=q, 1=k, 2=v (uniform per block)
    if (reg < 2) {
        // rope: lane holds col c; partner c^1 lives in lane lm^1
        const float qs = (reg == 0) ? (0.125f * 1.4426950408889634f) : 1.0f;
        const int odd = lm & 1;
#pragma unroll
        for (int m = 0; m < 4; ++m) {
#pragma unroll
            for (int r = 0; r < 4; ++r) {
                const int row = brow + wr * 64 + m * 16 + lg * 4 + r;
                const int s   = row & (SEQ - 1);
                const size_t base = (size_t)row * DQKV + bcol + wc * 64 + lm;
#pragma unroll
                for (int n = 0; n < 4; ++n) {
                    float v  = acc[m][n][r];
                    float pv = __shfl_xor(v, 1);
                    const int fi = (n * 16 + lm) >> 1;
                    float2 cs = reinterpret_cast<const float2*>(tab)[s * 32 + fi];
                    float c = cs.x * qs, sn = cs.y * qs;
                    float out = odd ? (pv * sn + v * c) : (v * c - pv * sn);
                    qkv[base + n * 16] = f2b(out);
                }
            }
        }
    } else {
        // v: write transposed. acc[m][n][0..3] are 4 consecutive rows (s).
        const int b = brow >> 11;
#pragma unroll
        for (int m = 0; m < 4; ++m) {
            const int s0 = (brow + wr * 64 + m * 16 + lg * 4) & (SEQ - 1);
#pragma unroll
            for (int n = 0; n < 4; ++n) {
                const int vcol = bcol + wc * 64 + n * 16 + lm - 2 * DM;
                const int h = vcol >> 6, d = vcol & 63;
                us4 val = { f2b(acc[m][n][0]), f2b(acc[m][n][1]),
                            f2b(acc[m][n][2]), f2b(acc[m][n][3]) };
                *reinterpret_cast<us4*>(vT + (size_t)((b * NH + h) * DH + d) * SEQ + s0) = val;
            }
        }
    }
}

// ---------------------------------------------------------------------------
// MFMA flash attention v9 (unchanged from round 11, 55 us verified).
// Block-shared LDS K/V staging, double-buffered; 64-query chunk per block;
// chunk pairing (31-c, c) -> every block exactly 33 iterations.
// XCD swizzle: bh & 7 == bid & 7. Swapped QK^T -> in-register softmax,
// defer-max, setprio. Both-sides XOR swizzle on K/V staging (rule #21).
// ---------------------------------------------------------------------------
__global__ __launch_bounds__(256, 2) void attn_mfma(const unsigned short* __restrict__ qkv,
                                                    const unsigned short* __restrict__ vT,
                                                    unsigned short* __restrict__ o) {
    const int tid  = threadIdx.x;
    const int wid  = tid >> 6;
    const int lane = tid & 63;
    const int lm = lane & 15, lg = lane >> 4;

    const int bid = blockIdx.x;             // [0,512)
    const int u   = bid >> 3;               // [0,64)
    const int bh  = (bid & 7) + 8 * (u >> 4);
    const int c0  = u & 15;                 // chunk-pair index
    const int b = bh >> 4, h = bh & 15;

    __shared__ unsigned short Kl[2][4096];     // 16 KB
    __shared__ unsigned short Vl[2][4096];     // 16 KB
    __shared__ unsigned int   Pex[4][16 * 34]; // 8.5 KB
    unsigned int* PW = Pex[wid];

    const unsigned short* kb = qkv + ((size_t)b * SEQ) * DQKV + DM + h * DH;
    const unsigned short* vb = vT + ((size_t)bh) * DH * SEQ;

    const int rloc = tid >> 3;               // 0..31
    const int cs   = (tid & 7) ^ (rloc & 7);
    const unsigned short* kst0 = kb + (size_t)rloc * DQKV + cs * 8;
    const unsigned short* kst1 = kb + (size_t)(rloc + 32) * DQKV + cs * 8;
    const unsigned short* vst0 = vb + (size_t)rloc * SEQ + cs * 8;
    const unsigned short* vst1 = vb + (size_t)(rloc + 32) * SEQ + cs * 8;
    const int sdst = wid * 512;

    const int sl0  = (lg ^ (lm & 7)) << 4;
    const int sl1  = ((lg + 4) ^ (lm & 7)) << 4;
    const int rowb = lm * 128;

    const int wr_base = lm * 34 + lg * 2;
    const int rd1 = lm * 34 + (lg >> 1) * 8 + (lg & 1) * 4;
    const int rd2 = rd1 + 16;

    for (int half = 0; half < 2; ++half) {
        const int c     = (half == 0) ? (31 - c0) : c0;
        const int qbase = c * 64 + wid * 16;
        const int nb    = c + 1;

        const unsigned short* qrow = qkv + ((size_t)(b * SEQ + qbase + lm)) * DQKV + h * DH;
        short8 qa0 = *reinterpret_cast<const short8*>(qrow + lg * 8);
        short8 qa1 = *reinterpret_cast<const short8*>(qrow + 32 + lg * 8);

        f32x4 o0 = {0.f, 0.f, 0.f, 0.f}, o1 = o0, o2 = o0, o3 = o0;
        float mrun = -INFINITY, lrun = 0.f;

        gload_lds16(kst0, &Kl[0][sdst]);
        gload_lds16(kst1, &Kl[0][2048 + sdst]);
        gload_lds16(vst0, &Vl[0][sdst]);
        gload_lds16(vst1, &Vl[0][2048 + sdst]);
        __syncthreads();

        int buf = 0;
        for (int blk = 0; blk < nb; ++blk) {
            const int kbase = blk << 6;

            if (blk + 1 < nb) {
                const size_t ko = (size_t)(kbase + 64) * DQKV;
                const int    vo = kbase + 64;
                gload_lds16(kst0 + ko, &Kl[buf ^ 1][sdst]);
                gload_lds16(kst1 + ko, &Kl[buf ^ 1][2048 + sdst]);
                gload_lds16(vst0 + vo, &Vl[buf ^ 1][sdst]);
                gload_lds16(vst1 + vo, &Vl[buf ^ 1][2048 + sdst]);
            }

            const char* Kb = (const char*)&Kl[buf][0];
            const char* Vb = (const char*)&Vl[buf][0];

            float s[16];
            __builtin_amdgcn_s_setprio(1);
#pragma unroll
            for (int st = 0; st < 4; ++st) {
                short8 k0 = *reinterpret_cast<const short8*>(Kb + st * 2048 + rowb + sl0);
                short8 k1 = *reinterpret_cast<const short8*>(Kb + st * 2048 + rowb + sl1);
                f32x4 t = {0.f, 0.f, 0.f, 0.f};
                t = __builtin_amdgcn_mfma_f32_16x16x32_bf16(k0, qa0, t, 0, 0, 0);
                t = __builtin_amdgcn_mfma_f32_16x16x32_bf16(k1, qa1, t, 0, 0, 0);
#pragma unroll
                for (int r = 0; r < 4; ++r) s[st * 4 + r] = t[r];
            }
            __builtin_amdgcn_s_setprio(0);

            short8 vf[8];
#pragma unroll
            for (int c4 = 0; c4 < 4; ++c4) {
                vf[c4 * 2]     = *reinterpret_cast<const short8*>(Vb + c4 * 2048 + rowb + sl0);
                vf[c4 * 2 + 1] = *reinterpret_cast<const short8*>(Vb + c4 * 2048 + rowb + sl1);
            }

            if (blk == nb - 1) {
#pragma unroll
                for (int st = 0; st < 4; ++st)
#pragma unroll
                    for (int r = 0; r < 4; ++r) {
                        int kk = kbase + st * 16 + lg * 4 + r;
                        s[st * 4 + r] = (kk <= qbase + lm) ? s[st * 4 + r] : -INFINITY;
                    }
            }

            float t0 = fmaxf(s[0], s[1]),  t1 = fmaxf(s[2], s[3]);
            float t2 = fmaxf(s[4], s[5]),  t3 = fmaxf(s[6], s[7]);
            float t4 = fmaxf(s[8], s[9]),  t5 = fmaxf(s[10], s[11]);
            float t6 = fmaxf(s[12], s[13]), t7 = fmaxf(s[14], s[15]);
            float lmax = fmaxf(fmaxf(fmaxf(t0, t1), fmaxf(t2, t3)),
                               fmaxf(fmaxf(t4, t5), fmaxf(t6, t7)));

            if (!__all(lmax - mrun <= 8.0f)) {
                float mx = lmax;
                mx = fmaxf(mx, __shfl_xor(mx, 16));
                mx = fmaxf(mx, __shfl_xor(mx, 32));
                float mn  = fmaxf(mrun, mx);
                float fsc = exp2f(mrun - mn);
                mrun = mn;
                lrun *= fsc;
                float fr[4];
#pragma unroll
                for (int r = 0; r < 4; ++r) fr[r] = __shfl(fsc, lg * 4 + r);
#pragma unroll
                for (int r = 0; r < 4; ++r) {
                    o0[r] *= fr[r]; o1[r] *= fr[r]; o2[r] *= fr[r]; o3[r] *= fr[r];
                }
            }

#pragma unroll
            for (int i = 0; i < 16; ++i) s[i] = exp2f(s[i] - mrun);
            float a0 = (s[0] + s[1]) + (s[2] + s[3]);
            float a1 = (s[4] + s[5]) + (s[6] + s[7]);
            float a2 = (s[8] + s[9]) + (s[10] + s[11]);
            float a3 = (s[12] + s[13]) + (s[14] + s[15]);
            float ps = (a0 + a1) + (a2 + a3);
            ps += __shfl_xor(ps, 16);
            ps += __shfl_xor(ps, 32);
            lrun += ps;

            // pack P via v_cvt_pk_bf16_f32 and relayout through LDS
#pragma unroll
            for (int st = 0; st < 4; ++st) {
                u32x2 w;
                w.x = pk2b(s[st * 4 + 0], s[st * 4 + 1]);
                w.y = pk2b(s[st * 4 + 2], s[st * 4 + 3]);
                *reinterpret_cast<u32x2*>(&PW[wr_base + st * 8]) = w;
            }
            __builtin_amdgcn_wave_barrier();
            asm volatile("" ::: "memory");

            union { unsigned int u[4]; short8 v; } pk1, pk2;
            {
                u32x2 x0 = *reinterpret_cast<const u32x2*>(&PW[rd1]);
                u32x2 x1 = *reinterpret_cast<const u32x2*>(&PW[rd1 + 2]);
                pk1.u[0] = x0.x; pk1.u[1] = x0.y; pk1.u[2] = x1.x; pk1.u[3] = x1.y;
                u32x2 y0 = *reinterpret_cast<const u32x2*>(&PW[rd2]);
                u32x2 y1 = *reinterpret_cast<const u32x2*>(&PW[rd2 + 2]);
                pk2.u[0] = y0.x; pk2.u[1] = y0.y; pk2.u[2] = y1.x; pk2.u[3] = y1.y;
            }
            __builtin_amdgcn_wave_barrier();
            asm volatile("" ::: "memory");

            __builtin_amdgcn_s_setprio(1);
            o0 = __builtin_amdgcn_mfma_f32_16x16x32_bf16(pk1.v, vf[0], o0, 0, 0, 0);
            o0 = __builtin_amdgcn_mfma_f32_16x16x32_bf16(pk2.v, vf[1], o0, 0, 0, 0);
            o1 = __builtin_amdgcn_mfma_f32_16x16x32_bf16(pk1.v, vf[2], o1, 0, 0, 0);
            o1 = __builtin_amdgcn_mfma_f32_16x16x32_bf16(pk2.v, vf[3], o1, 0, 0, 0);
            o2 = __builtin_amdgcn_mfma_f32_16x16x32_bf16(pk1.v, vf[4], o2, 0, 0, 0);
            o2 = __builtin_amdgcn_mfma_f32_16x16x32_bf16(pk2.v, vf[5], o2, 0, 0, 0);
            o3 = __builtin_amdgcn_mfma_f32_16x16x32_bf16(pk1.v, vf[6], o3, 0, 0, 0);
            o3 = __builtin_amdgcn_mfma_f32_16x16x32_bf16(pk2.v, vf[7], o3, 0, 0, 0);
            __builtin_amdgcn_s_setprio(0);

            __syncthreads();
            buf ^= 1;
        }

        float linv[4];
#pragma unroll
        for (int r = 0; r < 4; ++r) linv[r] = 1.0f / __shfl(lrun, lg * 4 + r);
#pragma unroll
        for (int r = 0; r < 4; ++r) {
            const size_t rowoff = ((size_t)(b * SEQ + qbase + lg * 4 + r)) * DM + h * DH;
            o[rowoff + 0 * 16 + lm] = f2b(o0[r] * linv[r]);
            o[rowoff + 1 * 16 + lm] = f2b(o1[r] * linv[r]);
            o[rowoff + 2 * 16 + lm] = f2b(o2[r] * linv[r]);
            o[rowoff + 3 * 16 + lm] = f2b(o3[r] * linv[r]);
        }
    }
}

// ---------------------------------------------------------------------------
extern "C" void kernel_launch(void* const* d_in, const int* in_sizes, int n_in,
                              void* d_out, int out_size, void* d_ws, size_t ws_size,
                              hipStream_t stream) {
    const float* x  = (const float*)d_in[0];
    const float* wq = (const float*)d_in[1];
    const float* wk = (const float*)d_in[2];
    const float* wv = (const float*)d_in[3];
    const float* wo = (const float*)d_in[4];
    float* out = (float*)d_out;

    char* ws = (char*)d_ws;
    const size_t MB = 1024 * 1024;
    unsigned short* xb      = (unsigned short*)(ws);             // 8 MB  (reused for attn_bf)
    unsigned short* wqkv    = (unsigned short*)(ws + 8 * MB);    // 6 MB
    unsigned short* wob     = (unsigned short*)(ws + 14 * MB);   // 2 MB
    unsigned short* qkv     = (unsigned short*)(ws + 16 * MB);   // 24 MB (q|k roped; v region unused)
    unsigned short* vT      = (unsigned short*)(ws + 40 * MB);   // 8 MB
    float*          ropetab = (float*)(ws + 48 * MB);            // 512 KB
    unsigned short* attn_bf = xb;                                // xb dead after QKV GEMM

    // 1: all conversions + rope table
    const int cvt_grid = (NX4 + 4 * NW4 + SEQ * 32) / 256;
    cvt_all<<<cvt_grid, 256, 0, stream>>>(x, wq, wk, wv, wo, xb, wqkv, wob, ropetab);

    // 2: fused QKV GEMM + RoPE + V-transpose (2-phase dbuf)
    gemm_qkv<<<dim3(DQKV / BN, MROWS / BM), 256, 0, stream>>>(xb, wqkv, qkv, vT, ropetab);

    // 3: flash attention
    attn_mfma<<<512, 256, 0, stream>>>(qkv, vT, attn_bf);

    // 4: output projection (128x64 tile, 512 blocks, 2-phase dbuf)
    gemm_out<<<dim3(DM / 64, MROWS / 128), 256, 0, stream>>>(attn_bf, wob, out);
}

// Round 13
// 122.098 us; speedup vs baseline: 2.6305x; 1.0330x over previous
//
#include <hip/hip_runtime.h>
#include <hip/hip_bf16.h>
#include <math.h>

// Problem constants
#define B_SZ   2
#define SEQ    2048
#define DM     1024
#define NH     16
#define DH     64
#define MROWS  (B_SZ * SEQ)      // 4096
#define DQKV   (3 * DM)          // 3072, interleaved qkv row stride

typedef __attribute__((ext_vector_type(8))) short short8;
typedef __attribute__((ext_vector_type(4))) float f32x4;
typedef __attribute__((ext_vector_type(16))) float f32x16;
typedef __attribute__((ext_vector_type(4))) unsigned short us4;
typedef __attribute__((ext_vector_type(2))) unsigned int u32x2;

__device__ __forceinline__ float b2f(unsigned short u) {
    union { float f; unsigned int i; } x; x.i = ((unsigned int)u) << 16; return x.f;
}
__device__ __forceinline__ unsigned short f2b(float f) {
    union { float f; unsigned int i; } x; x.f = f;
    return (unsigned short)((x.i + 0x7fffu + ((x.i >> 16) & 1u)) >> 16);
}
// packed f32x2 -> bf16x2 (compiler emits v_cvt_pk_bf16_f32)
__device__ __forceinline__ unsigned int pk2b(float a, float b) {
    float2 f2; f2.x = a; f2.y = b;
    __hip_bfloat162 hb = __float22bfloat162_rn(f2);
    return *reinterpret_cast<unsigned int*>(&hb);
}
// raw v_exp_f32 (exp2) — avoids OCML wrapper ops
__device__ __forceinline__ float fexp2(float x) {
    float r; asm("v_exp_f32 %0, %1" : "=v"(r) : "v"(x)); return r;
}
// v_permlane32_swap_b32: a[32..63] <-> b[0..31]
__device__ __forceinline__ void swap32(unsigned int& a, unsigned int& b) {
    asm("v_permlane32_swap_b32 %0, %1" : "+v"(a), "+v"(b));
}

// async global->LDS, 16B per lane; lds base must be wave-uniform (HW adds lane*16)
__device__ __forceinline__ void gload_lds16(const unsigned short* g, unsigned short* lds_base_uniform) {
    __builtin_amdgcn_global_load_lds(
        (const __attribute__((address_space(1))) unsigned int*)g,
        (__attribute__((address_space(3))) unsigned int*)lds_base_uniform,
        16, 0, 0);
}

// ---------------------------------------------------------------------------
// One-shot prep: x -> bf16, 4 weights -> bf16 (wq|wk|wv concat + wo),
// and the RoPE cos/sin table tab[s*32+i] = {cos,sin}(s * 10000^(-i/32)).
// ---------------------------------------------------------------------------
#define NX4 (MROWS * DM / 4)     // 2^20 vec4
#define NW4 (DM * DM / 4)        // 2^18 vec4

__global__ __launch_bounds__(256) void cvt_all(const float* __restrict__ x,
                                               const float* __restrict__ wq,
                                               const float* __restrict__ wk,
                                               const float* __restrict__ wv,
                                               const float* __restrict__ wo,
                                               unsigned short* __restrict__ xb,
                                               unsigned short* __restrict__ wqkv,
                                               unsigned short* __restrict__ wob,
                                               float* __restrict__ tab) {
    const int i = blockIdx.x * 256 + threadIdx.x;
    const int ncvt = NX4 + 4 * NW4;
    if (i < ncvt) {
        const float* src; unsigned short* dst; int off;
        if (i < NX4) { src = x; dst = xb; off = i; }
        else {
            int j = i - NX4;
            int w = j >> 18;
            off = j & (NW4 - 1);
            src = (w == 0) ? wq : (w == 1) ? wk : (w == 2) ? wv : wo;
            dst = (w < 3) ? wqkv + (size_t)w * DM * DM : wob;
        }
        float4 v = reinterpret_cast<const float4*>(src)[off];
        us4 o = { f2b(v.x), f2b(v.y), f2b(v.z), f2b(v.w) };
        reinterpret_cast<us4*>(dst)[off] = o;
    } else {
        int t = i - ncvt;               // [0, SEQ*32)
        if (t < SEQ * 32) {
            int s = t >> 5, fi = t & 31;
            float inv = powf(10000.0f, -(float)fi / 32.0f);
            float ang = (float)s * inv;
            tab[2 * t]     = cosf(ang);
            tab[2 * t + 1] = sinf(ang);
        }
    }
}

// ---------------------------------------------------------------------------
// 2-phase double-buffered bf16 MFMA GEMMs (unchanged from round 12).
// ---------------------------------------------------------------------------
#define BM 128
#define BN 128
#define BK 32

__global__ __launch_bounds__(256, 2) void gemm_out(const unsigned short* __restrict__ A,
                                                   const unsigned short* __restrict__ B,
                                                   float* __restrict__ Cout) {
    const int OBM = 128;
    __shared__ unsigned short As[2][OBM * BK];   // 2 x 8 KB
    __shared__ unsigned short Bs[2][64 * BK];    // 2 x 4 KB
    const int tid  = threadIdx.x;
    const int lane = tid & 63, wid = tid >> 6;
    const int lm = lane & 15, lg = lane >> 4;
    const int brow = blockIdx.y * OBM, bcol = blockIdx.x * 64;
    const int K = DM, N = DM;

    f32x4 acc[2][4] = {};

    const int rA  = tid >> 2;
    const int kc8 = (tid & 3) * 8;
    const unsigned short* gA0 = A + (size_t)(brow + rA) * K + kc8;
    const unsigned short* gA1 = A + (size_t)(brow + 64 + rA) * K + kc8;
    const unsigned short* gB0 = B + (size_t)(bcol + rA) * K + kc8;
    unsigned short* lA0 = (unsigned short*)As + wid * 512;
    unsigned short* lA1 = (unsigned short*)As + 2048 + wid * 512;
    unsigned short* lB0 = (unsigned short*)Bs + wid * 512;

    gload_lds16(gA0, lA0);
    gload_lds16(gA1, lA1);
    gload_lds16(gB0, lB0);
    __syncthreads();

    int buf = 0;
    for (int k0 = 0; k0 < K; k0 += BK) {
        if (k0 + BK < K) {
            gload_lds16(gA0 + k0 + BK, lA0 + (buf ^ 1) * 4096);
            gload_lds16(gA1 + k0 + BK, lA1 + (buf ^ 1) * 4096);
            gload_lds16(gB0 + k0 + BK, lB0 + (buf ^ 1) * 2048);
        }
        short8 a[2], b[4];
#pragma unroll
        for (int m = 0; m < 2; ++m)
            a[m] = *reinterpret_cast<const short8*>(&As[buf][(wid * 32 + m * 16 + lm) * BK + lg * 8]);
#pragma unroll
        for (int n = 0; n < 4; ++n)
            b[n] = *reinterpret_cast<const short8*>(&Bs[buf][(n * 16 + lm) * BK + lg * 8]);
#pragma unroll
        for (int m = 0; m < 2; ++m)
#pragma unroll
            for (int n = 0; n < 4; ++n)
                acc[m][n] = __builtin_amdgcn_mfma_f32_16x16x32_bf16(a[m], b[n], acc[m][n], 0, 0, 0);
        __syncthreads();
        buf ^= 1;
    }

#pragma unroll
    for (int m = 0; m < 2; ++m) {
#pragma unroll
        for (int r = 0; r < 4; ++r) {
            const size_t base = (size_t)(brow + wid * 32 + m * 16 + lg * 4 + r) * N + bcol + lm;
#pragma unroll
            for (int n = 0; n < 4; ++n)
                Cout[base + n * 16] = acc[m][n][r];
        }
    }
}

__global__ __launch_bounds__(256, 2) void gemm_qkv(const unsigned short* __restrict__ A,
                                                   const unsigned short* __restrict__ B,
                                                   unsigned short* __restrict__ qkv,
                                                   unsigned short* __restrict__ vT,
                                                   const float* __restrict__ tab) {
    __shared__ unsigned short As[2][BM * BK];
    __shared__ unsigned short Bs[2][BN * BK];
    const int tid  = threadIdx.x;
    const int lane = tid & 63, wid = tid >> 6;
    const int wr = wid >> 1, wc = wid & 1;
    const int lm = lane & 15, lg = lane >> 4;
    const int brow = blockIdx.y * BM, bcol = blockIdx.x * BN;
    const int K = DM;

    f32x4 acc[4][4] = {};

    const int rA  = tid >> 2;
    const int kc8 = (tid & 3) * 8;
    const unsigned short* gA0 = A + (size_t)(brow + rA) * K + kc8;
    const unsigned short* gA1 = A + (size_t)(brow + 64 + rA) * K + kc8;
    const unsigned short* gB0 = B + (size_t)(bcol + rA) * K + kc8;
    const unsigned short* gB1 = B + (size_t)(bcol + 64 + rA) * K + kc8;
    unsigned short* lA0 = (unsigned short*)As + wid * 512;
    unsigned short* lA1 = (unsigned short*)As + 2048 + wid * 512;
    unsigned short* lB0 = (unsigned short*)Bs + wid * 512;
    unsigned short* lB1 = (unsigned short*)Bs + 2048 + wid * 512;

    gload_lds16(gA0, lA0);
    gload_lds16(gA1, lA1);
    gload_lds16(gB0, lB0);
    gload_lds16(gB1, lB1);
    __syncthreads();

    int buf = 0;
    for (int k0 = 0; k0 < K; k0 += BK) {
        if (k0 + BK < K) {
            const int bo = (buf ^ 1) * 4096;
            gload_lds16(gA0 + k0 + BK, lA0 + bo);
            gload_lds16(gA1 + k0 + BK, lA1 + bo);
            gload_lds16(gB0 + k0 + BK, lB0 + bo);
            gload_lds16(gB1 + k0 + BK, lB1 + bo);
        }
        short8 a[4], b[4];
#pragma unroll
        for (int m = 0; m < 4; ++m)
            a[m] = *reinterpret_cast<const short8*>(&As[buf][(wr * 64 + m * 16 + lm) * BK + lg * 8]);
#pragma unroll
        for (int n = 0; n < 4; ++n)
            b[n] = *reinterpret_cast<const short8*>(&Bs[buf][(wc * 64 + n * 16 + lm) * BK + lg * 8]);
#pragma unroll
        for (int m = 0; m < 4; ++m)
#pragma unroll
            for (int n = 0; n < 4; ++n)
                acc[m][n] = __builtin_amdgcn_mfma_f32_16x16x32_bf16(a[m], b[n], acc[m][n], 0, 0, 0);
        __syncthreads();
        buf ^= 1;
    }

    const int reg = blockIdx.x >> 3;    // 0=q, 1=k, 2=v (uniform per block)
    if (reg < 2) {
        const float qs = (reg == 0) ? (0.125f * 1.4426950408889634f) : 1.0f;
        const int odd = lm & 1;
#pragma unroll
        for (int m = 0; m < 4; ++m) {
#pragma unroll
            for (int r = 0; r < 4; ++r) {
                const int row = brow + wr * 64 + m * 16 + lg * 4 + r;
                const int s   = row & (SEQ - 1);
                const size_t base = (size_t)row * DQKV + bcol + wc * 64 + lm;
#pragma unroll
                for (int n = 0; n < 4; ++n) {
                    float v  = acc[m][n][r];
                    float pv = __shfl_xor(v, 1);
                    const int fi = (n * 16 + lm) >> 1;
                    float2 cs = reinterpret_cast<const float2*>(tab)[s * 32 + fi];
                    float c = cs.x * qs, sn = cs.y * qs;
                    float out = odd ? (pv * sn + v * c) : (v * c - pv * sn);
                    qkv[base + n * 16] = f2b(out);
                }
            }
        }
    } else {
        const int b = brow >> 11;
#pragma unroll
        for (int m = 0; m < 4; ++m) {
            const int s0 = (brow + wr * 64 + m * 16 + lg * 4) & (SEQ - 1);
#pragma unroll
            for (int n = 0; n < 4; ++n) {
                const int vcol = bcol + wc * 64 + n * 16 + lm - 2 * DM;
                const int h = vcol >> 6, d = vcol & 63;
                us4 val = { f2b(acc[m][n][0]), f2b(acc[m][n][1]),
                            f2b(acc[m][n][2]), f2b(acc[m][n][3]) };
                *reinterpret_cast<us4*>(vT + (size_t)((b * NH + h) * DH + d) * SEQ + s0) = val;
            }
        }
    }
}

// ---------------------------------------------------------------------------
// MFMA flash attention v10: 32x32 MFMA, 32q per wave, 128q chunk per block.
// Swapped QK^T (S^T[k][q], q = lane&31); softmax cross-lane = 1 shfl_xor(32).
// P -> PV A-frag fully in-register: 16 cvt_pk + 8 permlane32_swap (no Pex).
// Block-shared LDS K/V (dbuf, XOR-swizzled both sides). Per-CU balance:
// co-resident blocks (u, u+32) get chunks c and 15-c (nb sum const = 34).
// All waves run nb = 2*chunk+2 iters (over-masked tail), aligned barriers.
// defer-max + setprio + raw v_exp_f32.
// ---------------------------------------------------------------------------
__global__ __launch_bounds__(256, 2) void attn_mfma(const unsigned short* __restrict__ qkv,
                                                    const unsigned short* __restrict__ vT,
                                                    unsigned short* __restrict__ o) {
    const int tid  = threadIdx.x;
    const int wid  = tid >> 6;
    const int lane = tid & 63;
    const int l31 = lane & 31, lo = lane >> 5;

    const int bid = blockIdx.x;             // [0,512)
    const int u   = bid >> 3;               // [0,64)
    const int j   = u & 31, hi = u >> 5;
    const int bh_hi = (hi ? 2 : 0) + (j >> 4);
    const int chunk = hi ? (15 - (j & 15)) : (j & 15);
    const int bh = (bid & 7) + 8 * bh_hi;
    const int b = bh >> 4, h = bh & 15;
    const int qbase = chunk * 128 + wid * 32;
    const int nb = 2 * chunk + 2;

    __shared__ unsigned short Kl[2][4096];     // 16 KB: K[64 keys][64 d], swizzled
    __shared__ unsigned short Vl[2][4096];     // 16 KB: V[64 d][64 keys], swizzled

    const unsigned short* kb = qkv + ((size_t)b * SEQ) * DQKV + DM + h * DH;
    const unsigned short* vb = vT + ((size_t)bh) * DH * SEQ;

    // staging (same proven pattern): stored slot tid&7 of row rloc; content
    // slot cs = (tid&7)^(rloc&7) pre-swizzled at the global source
    const int rloc = tid >> 3;
    const int cs   = (tid & 7) ^ (rloc & 7);
    const unsigned short* kst0 = kb + (size_t)rloc * DQKV + cs * 8;
    const unsigned short* kst1 = kb + (size_t)(rloc + 32) * DQKV + cs * 8;
    const unsigned short* vst0 = vb + (size_t)rloc * SEQ + cs * 8;
    const unsigned short* vst1 = vb + (size_t)(rloc + 32) * SEQ + cs * 8;
    const int sdst = wid * 512;

    // Q fragments: B-operand, col = q = l31, k_d = lo*8 + i per 16-d chunk
    const unsigned short* qr = qkv + ((size_t)(b * SEQ + qbase + l31)) * DQKV + h * DH + lo * 8;
    short8 qb4[4];
#pragma unroll
    for (int dc = 0; dc < 4; ++dc)
        qb4[dc] = *reinterpret_cast<const short8*>(qr + dc * 16);

    f32x16 oA = {0,0,0,0,0,0,0,0,0,0,0,0,0,0,0,0};
    f32x16 oB = {0,0,0,0,0,0,0,0,0,0,0,0,0,0,0,0};
    float mrun = -INFINITY, lrun = 0.f;

    gload_lds16(kst0, &Kl[0][sdst]);
    gload_lds16(kst1, &Kl[0][2048 + sdst]);
    gload_lds16(vst0, &Vl[0][sdst]);
    gload_lds16(vst1, &Vl[0][2048 + sdst]);
    __syncthreads();

    int buf = 0;
    for (int blk = 0; blk < nb; ++blk) {
        const int kbase = blk << 6;

        if (blk + 1 < nb) {
            const size_t ko = (size_t)(kbase + 64) * DQKV;
            const int    vo = kbase + 64;
            gload_lds16(kst0 + ko, &Kl[buf ^ 1][sdst]);
            gload_lds16(kst1 + ko, &Kl[buf ^ 1][2048 + sdst]);
            gload_lds16(vst0 + vo, &Vl[buf ^ 1][sdst]);
            gload_lds16(vst1 + vo, &Vl[buf ^ 1][2048 + sdst]);
        }

        const char* Kb = (const char*)&Kl[buf][0];
        const char* Vb = (const char*)&Vl[buf][0];

        // QK^T: S0 = keys kbase..+31, S1 = keys kbase+32..+63
        f32x16 S0 = {0,0,0,0,0,0,0,0,0,0,0,0,0,0,0,0};
        f32x16 S1 = {0,0,0,0,0,0,0,0,0,0,0,0,0,0,0,0};
        __builtin_amdgcn_s_setprio(1);
#pragma unroll
        for (int dc = 0; dc < 4; ++dc) {
            const int slot = dc * 2 + lo;
            short8 k0 = *reinterpret_cast<const short8*>(Kb + l31 * 128 + ((slot ^ (l31 & 7)) << 4));
            short8 k1 = *reinterpret_cast<const short8*>(Kb + (32 + l31) * 128 + ((slot ^ (l31 & 7)) << 4));
            S0 = __builtin_amdgcn_mfma_f32_32x32x16_bf16(k0, qb4[dc], S0, 0, 0, 0);
            S1 = __builtin_amdgcn_mfma_f32_32x32x16_bf16(k1, qb4[dc], S1, 0, 0, 0);
        }
        __builtin_amdgcn_s_setprio(0);

        // V fragments: B-operand, col = d = dh*32 + l31, k = kc*16 + lo*8 + i
        short8 vf[4][2];
#pragma unroll
        for (int kc = 0; kc < 4; ++kc) {
#pragma unroll
            for (int dh = 0; dh < 2; ++dh) {
                const int row = dh * 32 + l31;
                const int slot = kc * 2 + lo;
                vf[kc][dh] = *reinterpret_cast<const short8*>(Vb + row * 128 + ((slot ^ (row & 7)) << 4));
            }
        }

        float s0[16], s1[16];
#pragma unroll
        for (int r = 0; r < 16; ++r) { s0[r] = S0[r]; s1[r] = S1[r]; }

        // causal mask (only last two iters can cross any wave's diagonal)
        if (blk + 2 >= nb) {
            const int q = qbase + l31;
#pragma unroll
            for (int r = 0; r < 16; ++r) {
                const int kk = kbase + (r & 3) + 8 * (r >> 2) + 4 * lo;
                s0[r] = (kk <= q) ? s0[r] : -INFINITY;
                s1[r] = (kk + 32 <= q) ? s1[r] : -INFINITY;
            }
        }

        // in-lane max over 32 scores
        float tmax[8];
#pragma unroll
        for (int i = 0; i < 8; ++i)
            tmax[i] = fmaxf(fmaxf(s0[2 * i], s0[2 * i + 1]), fmaxf(s1[2 * i], s1[2 * i + 1]));
        float lmax = fmaxf(fmaxf(fmaxf(tmax[0], tmax[1]), fmaxf(tmax[2], tmax[3])),
                           fmaxf(fmaxf(tmax[4], tmax[5]), fmaxf(tmax[6], tmax[7])));

        // defer-max: cross-lane reduce + rescale only when needed
        if (!__all(lmax - mrun <= 8.0f)) {
            float mx = fmaxf(lmax, __shfl_xor(lmax, 32));
            float mn = fmaxf(mrun, mx);
            float fsc = fexp2(mrun - mn);
            mrun = mn;
            lrun *= fsc;
#pragma unroll
            for (int r = 0; r < 16; ++r) {
                float fr = __shfl(fsc, (r & 3) + 8 * (r >> 2) + 4 * lo);
                oA[r] *= fr; oB[r] *= fr;
            }
        }

        // P = exp2(S - mrun)
#pragma unroll
        for (int r = 0; r < 16; ++r) { s0[r] = fexp2(s0[r] - mrun); s1[r] = fexp2(s1[r] - mrun); }

        float ac[8];
#pragma unroll
        for (int i = 0; i < 8; ++i)
            ac[i] = (s0[2 * i] + s0[2 * i + 1]) + (s1[2 * i] + s1[2 * i + 1]);
        float ps = ((ac[0] + ac[1]) + (ac[2] + ac[3])) + ((ac[4] + ac[5]) + (ac[6] + ac[7]));
        ps += __shfl_xor(ps, 32);
        lrun += ps;

        // in-register P -> A-frag assembly: cvt_pk pairs + permlane32_swap.
        // For sub s: A-frag(kc=2s)   = {swap(pk(r0,r1),pk(r4,r5)), swap(pk(r2,r3),pk(r6,r7))}
        //            A-frag(kc=2s+1) = same with r8..r15
        unsigned int pf[4][4];
#pragma unroll
        for (int s = 0; s < 2; ++s) {
            const float* sp = s ? s1 : s0;
            unsigned int a0 = pk2b(sp[0], sp[1]);
            unsigned int b0 = pk2b(sp[4], sp[5]);
            swap32(a0, b0);
            unsigned int a1 = pk2b(sp[2], sp[3]);
            unsigned int b1 = pk2b(sp[6], sp[7]);
            swap32(a1, b1);
            pf[2 * s][0] = a0; pf[2 * s][1] = a1; pf[2 * s][2] = b0; pf[2 * s][3] = b1;
            unsigned int a2 = pk2b(sp[8], sp[9]);
            unsigned int b2 = pk2b(sp[12], sp[13]);
            swap32(a2, b2);
            unsigned int a3 = pk2b(sp[10], sp[11]);
            unsigned int b3 = pk2b(sp[14], sp[15]);
            swap32(a3, b3);
            pf[2 * s + 1][0] = a2; pf[2 * s + 1][1] = a3; pf[2 * s + 1][2] = b2; pf[2 * s + 1][3] = b3;
        }

        // PV: O[32q][64d] in two 32-d halves
        __builtin_amdgcn_s_setprio(1);
#pragma unroll
        for (int kc = 0; kc < 4; ++kc) {
            union { unsigned int u[4]; short8 v; } P;
            P.u[0] = pf[kc][0]; P.u[1] = pf[kc][1]; P.u[2] = pf[kc][2]; P.u[3] = pf[kc][3];
            oA = __builtin_amdgcn_mfma_f32_32x32x16_bf16(P.v, vf[kc][0], oA, 0, 0, 0);
            oB = __builtin_amdgcn_mfma_f32_32x32x16_bf16(P.v, vf[kc][1], oB, 0, 0, 0);
        }
        __builtin_amdgcn_s_setprio(0);

        __syncthreads();   // drains prefetch; buf^1 ready
        buf ^= 1;
    }

    // epilogue: O[q = (r&3)+8*(r>>2)+4*lo][d = dh*32 + l31]
    const float rl = 1.0f / lrun;
#pragma unroll
    for (int r = 0; r < 16; ++r) {
        const int qr = (r & 3) + 8 * (r >> 2) + 4 * lo;
        const float linv = __shfl(rl, qr);
        const size_t rowoff = ((size_t)(b * SEQ + qbase + qr)) * DM + h * DH;
        o[rowoff + l31]      = f2b(oA[r] * linv);
        o[rowoff + 32 + l31] = f2b(oB[r] * linv);
    }
}

// ---------------------------------------------------------------------------
extern "C" void kernel_launch(void* const* d_in, const int* in_sizes, int n_in,
                              void* d_out, int out_size, void* d_ws, size_t ws_size,
                              hipStream_t stream) {
    const float* x  = (const float*)d_in[0];
    const float* wq = (const float*)d_in[1];
    const float* wk = (const float*)d_in[2];
    const float* wv = (const float*)d_in[3];
    const float* wo = (const float*)d_in[4];
    float* out = (float*)d_out;

    char* ws = (char*)d_ws;
    const size_t MB = 1024 * 1024;
    unsigned short* xb      = (unsigned short*)(ws);             // 8 MB  (reused for attn_bf)
    unsigned short* wqkv    = (unsigned short*)(ws + 8 * MB);    // 6 MB
    unsigned short* wob     = (unsigned short*)(ws + 14 * MB);   // 2 MB
    unsigned short* qkv     = (unsigned short*)(ws + 16 * MB);   // 24 MB (q|k roped)
    unsigned short* vT      = (unsigned short*)(ws + 40 * MB);   // 8 MB
    float*          ropetab = (float*)(ws + 48 * MB);            // 512 KB
    unsigned short* attn_bf = xb;                                // xb dead after QKV GEMM

    // 1: all conversions + rope table
    const int cvt_grid = (NX4 + 4 * NW4 + SEQ * 32) / 256;
    cvt_all<<<cvt_grid, 256, 0, stream>>>(x, wq, wk, wv, wo, xb, wqkv, wob, ropetab);

    // 2: fused QKV GEMM + RoPE + V-transpose (2-phase dbuf)
    gemm_qkv<<<dim3(DQKV / BN, MROWS / BM), 256, 0, stream>>>(xb, wqkv, qkv, vT, ropetab);

    // 3: flash attention (32x32 MFMA, in-register P)
    attn_mfma<<<512, 256, 0, stream>>>(qkv, vT, attn_bf);

    // 4: output projection (128x64 tile, 512 blocks, 2-phase dbuf)
    gemm_out<<<dim3(DM / 64, MROWS / 128), 256, 0, stream>>>(attn_bf, wob, out);
}

// Round 14
// 117.504 us; speedup vs baseline: 2.7334x; 1.0391x over previous
//
#include <hip/hip_runtime.h>
#include <hip/hip_bf16.h>
#include <math.h>

// Problem constants
#define B_SZ   2
#define SEQ    2048
#define DM     1024
#define NH     16
#define DH     64
#define MROWS  (B_SZ * SEQ)      // 4096
#define DQKV   (3 * DM)          // 3072, interleaved qkv row stride

typedef __attribute__((ext_vector_type(8))) short short8;
typedef __attribute__((ext_vector_type(4))) float f32x4;
typedef __attribute__((ext_vector_type(16))) float f32x16;
typedef __attribute__((ext_vector_type(4))) unsigned short us4;
typedef __attribute__((ext_vector_type(2))) unsigned int u32x2;

__device__ __forceinline__ float b2f(unsigned short u) {
    union { float f; unsigned int i; } x; x.i = ((unsigned int)u) << 16; return x.f;
}
__device__ __forceinline__ unsigned short f2b(float f) {
    union { float f; unsigned int i; } x; x.f = f;
    return (unsigned short)((x.i + 0x7fffu + ((x.i >> 16) & 1u)) >> 16);
}
__device__ __forceinline__ unsigned int pk2b(float a, float b) {
    float2 f2; f2.x = a; f2.y = b;
    __hip_bfloat162 hb = __float22bfloat162_rn(f2);
    return *reinterpret_cast<unsigned int*>(&hb);
}
__device__ __forceinline__ float fexp2(float x) {
    float r; asm("v_exp_f32 %0, %1" : "=v"(r) : "v"(x)); return r;
}
__device__ __forceinline__ void swap32(unsigned int& a, unsigned int& b) {
    asm("v_permlane32_swap_b32 %0, %1" : "+v"(a), "+v"(b));
}

// async global->LDS, 16B per lane; lds base must be wave-uniform (HW adds lane*16)
__device__ __forceinline__ void gload_lds16(const unsigned short* g, unsigned short* lds_base_uniform) {
    __builtin_amdgcn_global_load_lds(
        (const __attribute__((address_space(1))) unsigned int*)g,
        (__attribute__((address_space(3))) unsigned int*)lds_base_uniform,
        16, 0, 0);
}

// ---------------------------------------------------------------------------
// One-shot prep: conversions + RoPE table.
// ---------------------------------------------------------------------------
#define NX4 (MROWS * DM / 4)     // 2^20 vec4
#define NW4 (DM * DM / 4)        // 2^18 vec4

__global__ __launch_bounds__(256) void cvt_all(const float* __restrict__ x,
                                               const float* __restrict__ wq,
                                               const float* __restrict__ wk,
                                               const float* __restrict__ wv,
                                               const float* __restrict__ wo,
                                               unsigned short* __restrict__ xb,
                                               unsigned short* __restrict__ wqkv,
                                               unsigned short* __restrict__ wob,
                                               float* __restrict__ tab) {
    const int i = blockIdx.x * 256 + threadIdx.x;
    const int ncvt = NX4 + 4 * NW4;
    if (i < ncvt) {
        const float* src; unsigned short* dst; int off;
        if (i < NX4) { src = x; dst = xb; off = i; }
        else {
            int j = i - NX4;
            int w = j >> 18;
            off = j & (NW4 - 1);
            src = (w == 0) ? wq : (w == 1) ? wk : (w == 2) ? wv : wo;
            dst = (w < 3) ? wqkv + (size_t)w * DM * DM : wob;
        }
        float4 v = reinterpret_cast<const float4*>(src)[off];
        us4 o = { f2b(v.x), f2b(v.y), f2b(v.z), f2b(v.w) };
        reinterpret_cast<us4*>(dst)[off] = o;
    } else {
        int t = i - ncvt;               // [0, SEQ*32)
        if (t < SEQ * 32) {
            int s = t >> 5, fi = t & 31;
            float inv = powf(10000.0f, -(float)fi / 32.0f);
            float ang = (float)s * inv;
            tab[2 * t]     = cosf(ang);
            tab[2 * t + 1] = sinf(ang);
        }
    }
}

// ---------------------------------------------------------------------------
// Triple-buffered counted-vmcnt bf16 MFMA GEMMs (T4 discipline):
// stage tile k+2, compute tile k, wait vmcnt(N) for tile k+1 only,
// raw s_barrier (no full drain in the loop).
// ---------------------------------------------------------------------------
#define BM 128
#define BN 128
#define BK 32

__global__ __launch_bounds__(256, 2) void gemm_out(const unsigned short* __restrict__ A,
                                                   const unsigned short* __restrict__ B,
                                                   float* __restrict__ Cout) {
    __shared__ unsigned short As[3][128 * BK];   // 3 x 8 KB
    __shared__ unsigned short Bs[3][64 * BK];    // 3 x 4 KB
    const int tid  = threadIdx.x;
    const int lane = tid & 63, wid = tid >> 6;
    const int lm = lane & 15, lg = lane >> 4;
    const int brow = blockIdx.y * 128, bcol = blockIdx.x * 64;
    const int K = DM, N = DM;
    const int NT = K / BK;     // 32

    f32x4 acc[2][4] = {};

    const int rA  = tid >> 2;
    const int kc8 = (tid & 3) * 8;
    const unsigned short* gA0 = A + (size_t)(brow + rA) * K + kc8;
    const unsigned short* gA1 = A + (size_t)(brow + 64 + rA) * K + kc8;
    const unsigned short* gB0 = B + (size_t)(bcol + rA) * K + kc8;
    const int la = wid * 512;

#define OSTAGE(t, bi)                                        \
    {                                                        \
        const int _o = (t) * BK;                             \
        gload_lds16(gA0 + _o, &As[bi][la]);                  \
        gload_lds16(gA1 + _o, &As[bi][2048 + la]);           \
        gload_lds16(gB0 + _o, &Bs[bi][la]);                  \
    }

    OSTAGE(0, 0);
    OSTAGE(1, 1);
    asm volatile("s_waitcnt vmcnt(3)" ::: "memory");
    __builtin_amdgcn_s_barrier();
    asm volatile("" ::: "memory");

    int cb = 0, sb = 2;
    for (int k = 0; k < NT; ++k) {
        if (k + 2 < NT) OSTAGE(k + 2, sb);
        short8 a[2], b[4];
#pragma unroll
        for (int m = 0; m < 2; ++m)
            a[m] = *reinterpret_cast<const short8*>(&As[cb][(wid * 32 + m * 16 + lm) * BK + lg * 8]);
#pragma unroll
        for (int n = 0; n < 4; ++n)
            b[n] = *reinterpret_cast<const short8*>(&Bs[cb][(n * 16 + lm) * BK + lg * 8]);
#pragma unroll
        for (int m = 0; m < 2; ++m)
#pragma unroll
            for (int n = 0; n < 4; ++n)
                acc[m][n] = __builtin_amdgcn_mfma_f32_16x16x32_bf16(a[m], b[n], acc[m][n], 0, 0, 0);
        if (k + 1 < NT) {
            if (k + 2 < NT) asm volatile("s_waitcnt vmcnt(3)" ::: "memory");
            else            asm volatile("s_waitcnt vmcnt(0)" ::: "memory");
            __builtin_amdgcn_s_barrier();
            asm volatile("" ::: "memory");
        }
        cb = (cb == 2) ? 0 : cb + 1;
        sb = (sb == 2) ? 0 : sb + 1;
    }
#undef OSTAGE

#pragma unroll
    for (int m = 0; m < 2; ++m) {
#pragma unroll
        for (int r = 0; r < 4; ++r) {
            const size_t base = (size_t)(brow + wid * 32 + m * 16 + lg * 4 + r) * N + bcol + lm;
#pragma unroll
            for (int n = 0; n < 4; ++n)
                Cout[base + n * 16] = acc[m][n][r];
        }
    }
}

__global__ __launch_bounds__(256, 2) void gemm_qkv(const unsigned short* __restrict__ A,
                                                   const unsigned short* __restrict__ B,
                                                   unsigned short* __restrict__ qkv,
                                                   unsigned short* __restrict__ vT,
                                                   const float* __restrict__ tab) {
    __shared__ unsigned short As[3][BM * BK];   // 3 x 8 KB
    __shared__ unsigned short Bs[3][BN * BK];   // 3 x 8 KB
    const int tid  = threadIdx.x;
    const int lane = tid & 63, wid = tid >> 6;
    const int wr = wid >> 1, wc = wid & 1;
    const int lm = lane & 15, lg = lane >> 4;
    const int brow = blockIdx.y * BM, bcol = blockIdx.x * BN;
    const int K = DM;
    const int NT = K / BK;     // 32

    f32x4 acc[4][4] = {};

    const int rA  = tid >> 2;
    const int kc8 = (tid & 3) * 8;
    const unsigned short* gA0 = A + (size_t)(brow + rA) * K + kc8;
    const unsigned short* gA1 = A + (size_t)(brow + 64 + rA) * K + kc8;
    const unsigned short* gB0 = B + (size_t)(bcol + rA) * K + kc8;
    const unsigned short* gB1 = B + (size_t)(bcol + 64 + rA) * K + kc8;
    const int la = wid * 512;

#define QSTAGE(t, bi)                                        \
    {                                                        \
        const int _o = (t) * BK;                             \
        gload_lds16(gA0 + _o, &As[bi][la]);                  \
        gload_lds16(gA1 + _o, &As[bi][2048 + la]);           \
        gload_lds16(gB0 + _o, &Bs[bi][la]);                  \
        gload_lds16(gB1 + _o, &Bs[bi][2048 + la]);           \
    }

    QSTAGE(0, 0);
    QSTAGE(1, 1);
    asm volatile("s_waitcnt vmcnt(4)" ::: "memory");
    __builtin_amdgcn_s_barrier();
    asm volatile("" ::: "memory");

    int cb = 0, sb = 2;
    for (int k = 0; k < NT; ++k) {
        if (k + 2 < NT) QSTAGE(k + 2, sb);
        short8 a[4], b[4];
#pragma unroll
        for (int m = 0; m < 4; ++m)
            a[m] = *reinterpret_cast<const short8*>(&As[cb][(wr * 64 + m * 16 + lm) * BK + lg * 8]);
#pragma unroll
        for (int n = 0; n < 4; ++n)
            b[n] = *reinterpret_cast<const short8*>(&Bs[cb][(wc * 64 + n * 16 + lm) * BK + lg * 8]);
#pragma unroll
        for (int m = 0; m < 4; ++m)
#pragma unroll
            for (int n = 0; n < 4; ++n)
                acc[m][n] = __builtin_amdgcn_mfma_f32_16x16x32_bf16(a[m], b[n], acc[m][n], 0, 0, 0);
        if (k + 1 < NT) {
            if (k + 2 < NT) asm volatile("s_waitcnt vmcnt(4)" ::: "memory");
            else            asm volatile("s_waitcnt vmcnt(0)" ::: "memory");
            __builtin_amdgcn_s_barrier();
            asm volatile("" ::: "memory");
        }
        cb = (cb == 2) ? 0 : cb + 1;
        sb = (sb == 2) ? 0 : sb + 1;
    }
#undef QSTAGE

    const int reg = blockIdx.x >> 3;    // 0=q, 1=k, 2=v (uniform per block)
    if (reg < 2) {
        const float qs = (reg == 0) ? (0.125f * 1.4426950408889634f) : 1.0f;
        const int odd = lm & 1;
#pragma unroll
        for (int m = 0; m < 4; ++m) {
#pragma unroll
            for (int r = 0; r < 4; ++r) {
                const int row = brow + wr * 64 + m * 16 + lg * 4 + r;
                const int s   = row & (SEQ - 1);
                const size_t base = (size_t)row * DQKV + bcol + wc * 64 + lm;
#pragma unroll
                for (int n = 0; n < 4; ++n) {
                    float v  = acc[m][n][r];
                    float pv = __shfl_xor(v, 1);
                    const int fi = (n * 16 + lm) >> 1;
                    float2 cs = reinterpret_cast<const float2*>(tab)[s * 32 + fi];
                    float c = cs.x * qs, sn = cs.y * qs;
                    float out = odd ? (pv * sn + v * c) : (v * c - pv * sn);
                    qkv[base + n * 16] = f2b(out);
                }
            }
        }
    } else {
        const int b = brow >> 11;
#pragma unroll
        for (int m = 0; m < 4; ++m) {
            const int s0 = (brow + wr * 64 + m * 16 + lg * 4) & (SEQ - 1);
#pragma unroll
            for (int n = 0; n < 4; ++n) {
                const int vcol = bcol + wc * 64 + n * 16 + lm - 2 * DM;
                const int h = vcol >> 6, d = vcol & 63;
                us4 val = { f2b(acc[m][n][0]), f2b(acc[m][n][1]),
                            f2b(acc[m][n][2]), f2b(acc[m][n][3]) };
                *reinterpret_cast<us4*>(vT + (size_t)((b * NH + h) * DH + d) * SEQ + s0) = val;
            }
        }
    }
}

// ---------------------------------------------------------------------------
// MFMA flash attention v11: 32x32 MFMA, 32q/wave, 128q chunk per block.
// K/V LDS as [32 physical rows][256B]: logical rows r and r+32 share a
// physical row; 4-bit slot XOR st = c16 ^ (pr&15) -> 2 lanes/slot = FREE
// (fixes v10's 4-way conflict from the 3-bit swizzle).
// Swapped QK^T, in-register softmax + cvt_pk/permlane P, defer-max,
// setprio, dbuf staging, per-CU chunk pairing (c, 15-c).
// ---------------------------------------------------------------------------
__global__ __launch_bounds__(256, 2) void attn_mfma(const unsigned short* __restrict__ qkv,
                                                    const unsigned short* __restrict__ vT,
                                                    unsigned short* __restrict__ o) {
    const int tid  = threadIdx.x;
    const int wid  = tid >> 6;
    const int lane = tid & 63;
    const int l31 = lane & 31, lo = lane >> 5;

    const int bid = blockIdx.x;             // [0,512)
    const int u   = bid >> 3;               // [0,64)
    const int j   = u & 31, hi = u >> 5;
    const int bh_hi = (hi ? 2 : 0) + (j >> 4);
    const int chunk = hi ? (15 - (j & 15)) : (j & 15);
    const int bh = (bid & 7) + 8 * bh_hi;
    const int b = bh >> 4, h = bh & 15;
    const int qbase = chunk * 128 + wid * 32;
    const int nb = 2 * chunk + 2;

    __shared__ unsigned short Kl[2][4096];     // [32 rows][256B], swizzled
    __shared__ unsigned short Vl[2][4096];

    const unsigned short* kb = qkv + ((size_t)b * SEQ) * DQKV + DM + h * DH;
    const unsigned short* vb = vT + ((size_t)bh) * DH * SEQ;

    // staging: thread tid fills stored slot st of physical row pr (+16 rnd 2);
    // content slot c16 = st ^ pr -> logical half hf = c16>>3, dims (c16&7)*8
    const int pr  = tid >> 4;               // 0..15
    const int st  = tid & 15;
    const int c16 = st ^ pr;
    const int hf  = c16 >> 3;
    const int cc  = c16 & 7;
    const unsigned short* kst0 = kb + (size_t)(pr + hf * 32) * DQKV + cc * 8;
    const unsigned short* kst1 = kst0 + (size_t)16 * DQKV;
    const unsigned short* vst0 = vb + (size_t)(pr + hf * 32) * SEQ + cc * 8;
    const unsigned short* vst1 = vst0 + 16 * SEQ;
    const int sdst = wid * 512;

    // Q fragments: B-operand, col = q = l31, k_d = lo*8 + i per 16-d chunk
    const unsigned short* qr = qkv + ((size_t)(b * SEQ + qbase + l31)) * DQKV + h * DH + lo * 8;
    short8 qb4[4];
#pragma unroll
    for (int dc = 0; dc < 4; ++dc)
        qb4[dc] = *reinterpret_cast<const short8*>(qr + dc * 16);

    f32x16 oA = {0,0,0,0,0,0,0,0,0,0,0,0,0,0,0,0};
    f32x16 oB = {0,0,0,0,0,0,0,0,0,0,0,0,0,0,0,0};
    float mrun = -INFINITY, lrun = 0.f;

    gload_lds16(kst0, &Kl[0][sdst]);
    gload_lds16(kst1, &Kl[0][2048 + sdst]);
    gload_lds16(vst0, &Vl[0][sdst]);
    gload_lds16(vst1, &Vl[0][2048 + sdst]);
    __syncthreads();

    const int lx = l31 & 15;
    int buf = 0;
    for (int blk = 0; blk < nb; ++blk) {
        const int kbase = blk << 6;

        if (blk + 1 < nb) {
            const size_t ko = (size_t)(kbase + 64) * DQKV;
            const int    vo = kbase + 64;
            gload_lds16(kst0 + ko, &Kl[buf ^ 1][sdst]);
            gload_lds16(kst1 + ko, &Kl[buf ^ 1][2048 + sdst]);
            gload_lds16(vst0 + vo, &Vl[buf ^ 1][sdst]);
            gload_lds16(vst1 + vo, &Vl[buf ^ 1][2048 + sdst]);
        }

        const char* Kb = (const char*)&Kl[buf][0];
        const char* Vb = (const char*)&Vl[buf][0];

        // QK^T: S0 = keys kbase..+31 (hf=0), S1 = +32..+63 (hf=1)
        f32x16 S0 = {0,0,0,0,0,0,0,0,0,0,0,0,0,0,0,0};
        f32x16 S1 = {0,0,0,0,0,0,0,0,0,0,0,0,0,0,0,0};
        __builtin_amdgcn_s_setprio(1);
#pragma unroll
        for (int dc = 0; dc < 4; ++dc) {
            const int s0s = ((dc * 2 + lo)     ^ lx) << 4;
            const int s1s = ((8 + dc * 2 + lo) ^ lx) << 4;
            short8 k0 = *reinterpret_cast<const short8*>(Kb + l31 * 256 + s0s);
            short8 k1 = *reinterpret_cast<const short8*>(Kb + l31 * 256 + s1s);
            S0 = __builtin_amdgcn_mfma_f32_32x32x16_bf16(k0, qb4[dc], S0, 0, 0, 0);
            S1 = __builtin_amdgcn_mfma_f32_32x32x16_bf16(k1, qb4[dc], S1, 0, 0, 0);
        }
        __builtin_amdgcn_s_setprio(0);

        // V fragments: logical d = dh*32 + l31 -> phys row l31, half dh
        short8 vf[4][2];
#pragma unroll
        for (int kc = 0; kc < 4; ++kc) {
#pragma unroll
            for (int dh = 0; dh < 2; ++dh) {
                const int sts = ((dh * 8 + kc * 2 + lo) ^ lx) << 4;
                vf[kc][dh] = *reinterpret_cast<const short8*>(Vb + l31 * 256 + sts);
            }
        }

        float s0[16], s1[16];
#pragma unroll
        for (int r = 0; r < 16; ++r) { s0[r] = S0[r]; s1[r] = S1[r]; }

        // causal mask (only last two iters can cross any wave's diagonal)
        if (blk + 2 >= nb) {
            const int q = qbase + l31;
#pragma unroll
            for (int r = 0; r < 16; ++r) {
                const int kk = kbase + (r & 3) + 8 * (r >> 2) + 4 * lo;
                s0[r] = (kk <= q) ? s0[r] : -INFINITY;
                s1[r] = (kk + 32 <= q) ? s1[r] : -INFINITY;
            }
        }

        // in-lane max over 32 scores
        float tmax[8];
#pragma unroll
        for (int i = 0; i < 8; ++i)
            tmax[i] = fmaxf(fmaxf(s0[2 * i], s0[2 * i + 1]), fmaxf(s1[2 * i], s1[2 * i + 1]));
        float lmax = fmaxf(fmaxf(fmaxf(tmax[0], tmax[1]), fmaxf(tmax[2], tmax[3])),
                           fmaxf(fmaxf(tmax[4], tmax[5]), fmaxf(tmax[6], tmax[7])));

        // defer-max
        if (!__all(lmax - mrun <= 8.0f)) {
            float mx = fmaxf(lmax, __shfl_xor(lmax, 32));
            float mn = fmaxf(mrun, mx);
            float fsc = fexp2(mrun - mn);
            mrun = mn;
            lrun *= fsc;
#pragma unroll
            for (int r = 0; r < 16; ++r) {
                float fr = __shfl(fsc, (r & 3) + 8 * (r >> 2) + 4 * lo);
                oA[r] *= fr; oB[r] *= fr;
            }
        }

        // P = exp2(S - mrun)
#pragma unroll
        for (int r = 0; r < 16; ++r) { s0[r] = fexp2(s0[r] - mrun); s1[r] = fexp2(s1[r] - mrun); }

        float ac[8];
#pragma unroll
        for (int i = 0; i < 8; ++i)
            ac[i] = (s0[2 * i] + s0[2 * i + 1]) + (s1[2 * i] + s1[2 * i + 1]);
        float ps = ((ac[0] + ac[1]) + (ac[2] + ac[3])) + ((ac[4] + ac[5]) + (ac[6] + ac[7]));
        ps += __shfl_xor(ps, 32);
        lrun += ps;

        // in-register P -> A-frag: cvt_pk pairs + permlane32_swap
        unsigned int pf[4][4];
#pragma unroll
        for (int s = 0; s < 2; ++s) {
            const float* sp = s ? s1 : s0;
            unsigned int a0 = pk2b(sp[0], sp[1]);
            unsigned int b0 = pk2b(sp[4], sp[5]);
            swap32(a0, b0);
            unsigned int a1 = pk2b(sp[2], sp[3]);
            unsigned int b1 = pk2b(sp[6], sp[7]);
            swap32(a1, b1);
            pf[2 * s][0] = a0; pf[2 * s][1] = a1; pf[2 * s][2] = b0; pf[2 * s][3] = b1;
            unsigned int a2 = pk2b(sp[8], sp[9]);
            unsigned int b2 = pk2b(sp[12], sp[13]);
            swap32(a2, b2);
            unsigned int a3 = pk2b(sp[10], sp[11]);
            unsigned int b3 = pk2b(sp[14], sp[15]);
            swap32(a3, b3);
            pf[2 * s + 1][0] = a2; pf[2 * s + 1][1] = a3; pf[2 * s + 1][2] = b2; pf[2 * s + 1][3] = b3;
        }

        // PV: O[32q][64d] in two 32-d halves
        __builtin_amdgcn_s_setprio(1);
#pragma unroll
        for (int kc = 0; kc < 4; ++kc) {
            union { unsigned int u[4]; short8 v; } P;
            P.u[0] = pf[kc][0]; P.u[1] = pf[kc][1]; P.u[2] = pf[kc][2]; P.u[3] = pf[kc][3];
            oA = __builtin_amdgcn_mfma_f32_32x32x16_bf16(P.v, vf[kc][0], oA, 0, 0, 0);
            oB = __builtin_amdgcn_mfma_f32_32x32x16_bf16(P.v, vf[kc][1], oB, 0, 0, 0);
        }
        __builtin_amdgcn_s_setprio(0);

        __syncthreads();   // drains prefetch; buf^1 ready
        buf ^= 1;
    }

    // epilogue
    const float rl = 1.0f / lrun;
#pragma unroll
    for (int r = 0; r < 16; ++r) {
        const int qr2 = (r & 3) + 8 * (r >> 2) + 4 * lo;
        const float linv = __shfl(rl, qr2);
        const size_t rowoff = ((size_t)(b * SEQ + qbase + qr2)) * DM + h * DH;
        o[rowoff + l31]      = f2b(oA[r] * linv);
        o[rowoff + 32 + l31] = f2b(oB[r] * linv);
    }
}

// ---------------------------------------------------------------------------
extern "C" void kernel_launch(void* const* d_in, const int* in_sizes, int n_in,
                              void* d_out, int out_size, void* d_ws, size_t ws_size,
                              hipStream_t stream) {
    const float* x  = (const float*)d_in[0];
    const float* wq = (const float*)d_in[1];
    const float* wk = (const float*)d_in[2];
    const float* wv = (const float*)d_in[3];
    const float* wo = (const float*)d_in[4];
    float* out = (float*)d_out;

    char* ws = (char*)d_ws;
    const size_t MB = 1024 * 1024;
    unsigned short* xb      = (unsigned short*)(ws);             // 8 MB (reused for attn_bf)
    unsigned short* wqkv    = (unsigned short*)(ws + 8 * MB);    // 6 MB
    unsigned short* wob     = (unsigned short*)(ws + 14 * MB);   // 2 MB
    unsigned short* qkv     = (unsigned short*)(ws + 16 * MB);   // 24 MB
    unsigned short* vT      = (unsigned short*)(ws + 40 * MB);   // 8 MB
    float*          ropetab = (float*)(ws + 48 * MB);            // 512 KB
    unsigned short* attn_bf = xb;

    const int cvt_grid = (NX4 + 4 * NW4 + SEQ * 32) / 256;
    cvt_all<<<cvt_grid, 256, 0, stream>>>(x, wq, wk, wv, wo, xb, wqkv, wob, ropetab);

    gemm_qkv<<<dim3(DQKV / BN, MROWS / BM), 256, 0, stream>>>(xb, wqkv, qkv, vT, ropetab);

    attn_mfma<<<512, 256, 0, stream>>>(qkv, vT, attn_bf);

    gemm_out<<<dim3(DM / 64, MROWS / 128), 256, 0, stream>>>(attn_bf, wob, out);
}

// Round 15
// 112.739 us; speedup vs baseline: 2.8489x; 1.0423x over previous
//
#include <hip/hip_runtime.h>
#include <hip/hip_bf16.h>
#include <math.h>

// Problem constants
#define B_SZ   2
#define SEQ    2048
#define DM     1024
#define NH     16
#define DH     64
#define MROWS  (B_SZ * SEQ)      // 4096
#define DQKV   (3 * DM)          // 3072, interleaved qkv row stride

typedef __attribute__((ext_vector_type(8))) short short8;
typedef __attribute__((ext_vector_type(4))) float f32x4;
typedef __attribute__((ext_vector_type(16))) float f32x16;
typedef __attribute__((ext_vector_type(4))) unsigned short us4;
typedef __attribute__((ext_vector_type(2))) unsigned int u32x2;

__device__ __forceinline__ float b2f(unsigned short u) {
    union { float f; unsigned int i; } x; x.i = ((unsigned int)u) << 16; return x.f;
}
__device__ __forceinline__ unsigned short f2b(float f) {
    union { float f; unsigned int i; } x; x.f = f;
    return (unsigned short)((x.i + 0x7fffu + ((x.i >> 16) & 1u)) >> 16);
}
__device__ __forceinline__ unsigned int pk2b(float a, float b) {
    float2 f2; f2.x = a; f2.y = b;
    __hip_bfloat162 hb = __float22bfloat162_rn(f2);
    return *reinterpret_cast<unsigned int*>(&hb);
}
__device__ __forceinline__ float fexp2(float x) {
    float r; asm("v_exp_f32 %0, %1" : "=v"(r) : "v"(x)); return r;
}
__device__ __forceinline__ void swap32(unsigned int& a, unsigned int& b) {
    asm("v_permlane32_swap_b32 %0, %1" : "+v"(a), "+v"(b));
}

// async global->LDS, 16B per lane; lds base must be wave-uniform (HW adds lane*16)
__device__ __forceinline__ void gload_lds16(const unsigned short* g, unsigned short* lds_base_uniform) {
    __builtin_amdgcn_global_load_lds(
        (const __attribute__((address_space(1))) unsigned int*)g,
        (__attribute__((address_space(3))) unsigned int*)lds_base_uniform,
        16, 0, 0);
}

// ---------------------------------------------------------------------------
// One-shot prep: conversions + RoPE table.
// ---------------------------------------------------------------------------
#define NX4 (MROWS * DM / 4)     // 2^20 vec4
#define NW4 (DM * DM / 4)        // 2^18 vec4

__global__ __launch_bounds__(256) void cvt_all(const float* __restrict__ x,
                                               const float* __restrict__ wq,
                                               const float* __restrict__ wk,
                                               const float* __restrict__ wv,
                                               const float* __restrict__ wo,
                                               unsigned short* __restrict__ xb,
                                               unsigned short* __restrict__ wqkv,
                                               unsigned short* __restrict__ wob,
                                               float* __restrict__ tab) {
    const int i = blockIdx.x * 256 + threadIdx.x;
    const int ncvt = NX4 + 4 * NW4;
    if (i < ncvt) {
        const float* src; unsigned short* dst; int off;
        if (i < NX4) { src = x; dst = xb; off = i; }
        else {
            int j = i - NX4;
            int w = j >> 18;
            off = j & (NW4 - 1);
            src = (w == 0) ? wq : (w == 1) ? wk : (w == 2) ? wv : wo;
            dst = (w < 3) ? wqkv + (size_t)w * DM * DM : wob;
        }
        float4 v = reinterpret_cast<const float4*>(src)[off];
        us4 o = { f2b(v.x), f2b(v.y), f2b(v.z), f2b(v.w) };
        reinterpret_cast<us4*>(dst)[off] = o;
    } else {
        int t = i - ncvt;               // [0, SEQ*32)
        if (t < SEQ * 32) {
            int s = t >> 5, fi = t & 31;
            float inv = powf(10000.0f, -(float)fi / 32.0f);
            float ang = (float)s * inv;
            tab[2 * t]     = cosf(ang);
            tab[2 * t + 1] = sinf(ang);
        }
    }
}

// ---------------------------------------------------------------------------
// Triple-buffered counted-vmcnt bf16 MFMA GEMMs (unchanged from round 14).
// ---------------------------------------------------------------------------
#define BM 128
#define BN 128
#define BK 32

__global__ __launch_bounds__(256, 2) void gemm_out(const unsigned short* __restrict__ A,
                                                   const unsigned short* __restrict__ B,
                                                   float* __restrict__ Cout) {
    __shared__ unsigned short As[3][128 * BK];   // 3 x 8 KB
    __shared__ unsigned short Bs[3][64 * BK];    // 3 x 4 KB
    const int tid  = threadIdx.x;
    const int lane = tid & 63, wid = tid >> 6;
    const int lm = lane & 15, lg = lane >> 4;
    const int brow = blockIdx.y * 128, bcol = blockIdx.x * 64;
    const int K = DM, N = DM;
    const int NT = K / BK;     // 32

    f32x4 acc[2][4] = {};

    const int rA  = tid >> 2;
    const int kc8 = (tid & 3) * 8;
    const unsigned short* gA0 = A + (size_t)(brow + rA) * K + kc8;
    const unsigned short* gA1 = A + (size_t)(brow + 64 + rA) * K + kc8;
    const unsigned short* gB0 = B + (size_t)(bcol + rA) * K + kc8;
    const int la = wid * 512;

#define OSTAGE(t, bi)                                        \
    {                                                        \
        const int _o = (t) * BK;                             \
        gload_lds16(gA0 + _o, &As[bi][la]);                  \
        gload_lds16(gA1 + _o, &As[bi][2048 + la]);           \
        gload_lds16(gB0 + _o, &Bs[bi][la]);                  \
    }

    OSTAGE(0, 0);
    OSTAGE(1, 1);
    asm volatile("s_waitcnt vmcnt(3)" ::: "memory");
    __builtin_amdgcn_s_barrier();
    asm volatile("" ::: "memory");

    int cb = 0, sb = 2;
    for (int k = 0; k < NT; ++k) {
        if (k + 2 < NT) OSTAGE(k + 2, sb);
        short8 a[2], b[4];
#pragma unroll
        for (int m = 0; m < 2; ++m)
            a[m] = *reinterpret_cast<const short8*>(&As[cb][(wid * 32 + m * 16 + lm) * BK + lg * 8]);
#pragma unroll
        for (int n = 0; n < 4; ++n)
            b[n] = *reinterpret_cast<const short8*>(&Bs[cb][(n * 16 + lm) * BK + lg * 8]);
#pragma unroll
        for (int m = 0; m < 2; ++m)
#pragma unroll
            for (int n = 0; n < 4; ++n)
                acc[m][n] = __builtin_amdgcn_mfma_f32_16x16x32_bf16(a[m], b[n], acc[m][n], 0, 0, 0);
        if (k + 1 < NT) {
            if (k + 2 < NT) asm volatile("s_waitcnt vmcnt(3)" ::: "memory");
            else            asm volatile("s_waitcnt vmcnt(0)" ::: "memory");
            __builtin_amdgcn_s_barrier();
            asm volatile("" ::: "memory");
        }
        cb = (cb == 2) ? 0 : cb + 1;
        sb = (sb == 2) ? 0 : sb + 1;
    }
#undef OSTAGE

#pragma unroll
    for (int m = 0; m < 2; ++m) {
#pragma unroll
        for (int r = 0; r < 4; ++r) {
            const size_t base = (size_t)(brow + wid * 32 + m * 16 + lg * 4 + r) * N + bcol + lm;
#pragma unroll
            for (int n = 0; n < 4; ++n)
                Cout[base + n * 16] = acc[m][n][r];
        }
    }
}

__global__ __launch_bounds__(256, 2) void gemm_qkv(const unsigned short* __restrict__ A,
                                                   const unsigned short* __restrict__ B,
                                                   unsigned short* __restrict__ qkv,
                                                   unsigned short* __restrict__ vT,
                                                   const float* __restrict__ tab) {
    __shared__ unsigned short As[3][BM * BK];   // 3 x 8 KB
    __shared__ unsigned short Bs[3][BN * BK];   // 3 x 8 KB
    const int tid  = threadIdx.x;
    const int lane = tid & 63, wid = tid >> 6;
    const int wr = wid >> 1, wc = wid & 1;
    const int lm = lane & 15, lg = lane >> 4;
    const int brow = blockIdx.y * BM, bcol = blockIdx.x * BN;
    const int K = DM;
    const int NT = K / BK;     // 32

    f32x4 acc[4][4] = {};

    const int rA  = tid >> 2;
    const int kc8 = (tid & 3) * 8;
    const unsigned short* gA0 = A + (size_t)(brow + rA) * K + kc8;
    const unsigned short* gA1 = A + (size_t)(brow + 64 + rA) * K + kc8;
    const unsigned short* gB0 = B + (size_t)(bcol + rA) * K + kc8;
    const unsigned short* gB1 = B + (size_t)(bcol + 64 + rA) * K + kc8;
    const int la = wid * 512;

#define QSTAGE(t, bi)                                        \
    {                                                        \
        const int _o = (t) * BK;                             \
        gload_lds16(gA0 + _o, &As[bi][la]);                  \
        gload_lds16(gA1 + _o, &As[bi][2048 + la]);           \
        gload_lds16(gB0 + _o, &Bs[bi][la]);                  \
        gload_lds16(gB1 + _o, &Bs[bi][2048 + la]);           \
    }

    QSTAGE(0, 0);
    QSTAGE(1, 1);
    asm volatile("s_waitcnt vmcnt(4)" ::: "memory");
    __builtin_amdgcn_s_barrier();
    asm volatile("" ::: "memory");

    int cb = 0, sb = 2;
    for (int k = 0; k < NT; ++k) {
        if (k + 2 < NT) QSTAGE(k + 2, sb);
        short8 a[4], b[4];
#pragma unroll
        for (int m = 0; m < 4; ++m)
            a[m] = *reinterpret_cast<const short8*>(&As[cb][(wr * 64 + m * 16 + lm) * BK + lg * 8]);
#pragma unroll
        for (int n = 0; n < 4; ++n)
            b[n] = *reinterpret_cast<const short8*>(&Bs[cb][(wc * 64 + n * 16 + lm) * BK + lg * 8]);
#pragma unroll
        for (int m = 0; m < 4; ++m)
#pragma unroll
            for (int n = 0; n < 4; ++n)
                acc[m][n] = __builtin_amdgcn_mfma_f32_16x16x32_bf16(a[m], b[n], acc[m][n], 0, 0, 0);
        if (k + 1 < NT) {
            if (k + 2 < NT) asm volatile("s_waitcnt vmcnt(4)" ::: "memory");
            else            asm volatile("s_waitcnt vmcnt(0)" ::: "memory");
            __builtin_amdgcn_s_barrier();
            asm volatile("" ::: "memory");
        }
        cb = (cb == 2) ? 0 : cb + 1;
        sb = (sb == 2) ? 0 : sb + 1;
    }
#undef QSTAGE

    const int reg = blockIdx.x >> 3;    // 0=q, 1=k, 2=v (uniform per block)
    if (reg < 2) {
        const float qs = (reg == 0) ? (0.125f * 1.4426950408889634f) : 1.0f;
        const int odd = lm & 1;
#pragma unroll
        for (int m = 0; m < 4; ++m) {
#pragma unroll
            for (int r = 0; r < 4; ++r) {
                const int row = brow + wr * 64 + m * 16 + lg * 4 + r;
                const int s   = row & (SEQ - 1);
                const size_t base = (size_t)row * DQKV + bcol + wc * 64 + lm;
#pragma unroll
                for (int n = 0; n < 4; ++n) {
                    float v  = acc[m][n][r];
                    float pv = __shfl_xor(v, 1);
                    const int fi = (n * 16 + lm) >> 1;
                    float2 cs = reinterpret_cast<const float2*>(tab)[s * 32 + fi];
                    float c = cs.x * qs, sn = cs.y * qs;
                    float out = odd ? (pv * sn + v * c) : (v * c - pv * sn);
                    qkv[base + n * 16] = f2b(out);
                }
            }
        }
    } else {
        const int b = brow >> 11;
#pragma unroll
        for (int m = 0; m < 4; ++m) {
            const int s0 = (brow + wr * 64 + m * 16 + lg * 4) & (SEQ - 1);
#pragma unroll
            for (int n = 0; n < 4; ++n) {
                const int vcol = bcol + wc * 64 + n * 16 + lm - 2 * DM;
                const int h = vcol >> 6, d = vcol & 63;
                us4 val = { f2b(acc[m][n][0]), f2b(acc[m][n][1]),
                            f2b(acc[m][n][2]), f2b(acc[m][n][3]) };
                *reinterpret_cast<us4*>(vT + (size_t)((b * NH + h) * DH + d) * SEQ + s0) = val;
            }
        }
    }
}

// ---------------------------------------------------------------------------
// MFMA flash attention v12: split-K wave pairs (see header comment above).
// ---------------------------------------------------------------------------
__global__ __launch_bounds__(256, 4) void attn_mfma(const unsigned short* __restrict__ qkv,
                                                    const unsigned short* __restrict__ vT,
                                                    unsigned short* __restrict__ o) {
    const int tid  = threadIdx.x;
    const int wid  = tid >> 6;
    const int lane = tid & 63;
    const int l31 = lane & 31, lo = lane >> 5;
    const int tile = wid >> 1;       // 0,1: q sub-tile
    const int half = wid & 1;        // 0,1: key half

    const int bid = blockIdx.x;      // [0,1024)
    const int u   = bid >> 3;        // [0,128)
    const int j   = u & 31;
    const int bh_hi = u >> 5;        // 0..3
    const int chunk = (bh_hi & 1) ? (31 - j) : j;
    const int bh = (bid & 7) + 8 * bh_hi;
    const int b = bh >> 4, h = bh & 15;
    const int qbase = chunk * 64 + tile * 32;
    const int nb = chunk + 1;

    __shared__ unsigned short Kl[2][4096];     // [32 rows][256B], swizzled (16KB)
    __shared__ unsigned short Vl[2][4096];     // (16KB)

    const unsigned short* kb = qkv + ((size_t)b * SEQ) * DQKV + DM + h * DH;
    const unsigned short* vb = vT + ((size_t)bh) * DH * SEQ;

    const int pr  = tid >> 4;               // 0..15
    const int st  = tid & 15;
    const int c16 = st ^ pr;
    const int hf  = c16 >> 3;
    const int cc  = c16 & 7;
    const unsigned short* kst0 = kb + (size_t)(pr + hf * 32) * DQKV + cc * 8;
    const unsigned short* kst1 = kst0 + (size_t)16 * DQKV;
    const unsigned short* vst0 = vb + (size_t)(pr + hf * 32) * SEQ + cc * 8;
    const unsigned short* vst1 = vst0 + 16 * SEQ;
    const int sdst = wid * 512;

    const unsigned short* qr = qkv + ((size_t)(b * SEQ + qbase + l31)) * DQKV + h * DH + lo * 8;
    short8 qb4[4];
#pragma unroll
    for (int dc = 0; dc < 4; ++dc)
        qb4[dc] = *reinterpret_cast<const short8*>(qr + dc * 16);

    f32x16 oA = {0,0,0,0,0,0,0,0,0,0,0,0,0,0,0,0};
    f32x16 oB = {0,0,0,0,0,0,0,0,0,0,0,0,0,0,0,0};
    float mrun = -3.0e38f, lrun = 0.f;

    gload_lds16(kst0, &Kl[0][sdst]);
    gload_lds16(kst1, &Kl[0][2048 + sdst]);
    gload_lds16(vst0, &Vl[0][sdst]);
    gload_lds16(vst1, &Vl[0][2048 + sdst]);
    __syncthreads();

    const int lx = l31 & 15;
    int buf = 0;
    for (int blk = 0; blk < nb; ++blk) {
        const int kbase = blk << 6;

        if (blk + 1 < nb) {
            const size_t ko = (size_t)(kbase + 64) * DQKV;
            const int    vo = kbase + 64;
            gload_lds16(kst0 + ko, &Kl[buf ^ 1][sdst]);
            gload_lds16(kst1 + ko, &Kl[buf ^ 1][2048 + sdst]);
            gload_lds16(vst0 + vo, &Vl[buf ^ 1][sdst]);
            gload_lds16(vst1 + vo, &Vl[buf ^ 1][2048 + sdst]);
        }

        const char* Kb = (const char*)&Kl[buf][0];
        const char* Vb = (const char*)&Vl[buf][0];

        f32x16 S = {0,0,0,0,0,0,0,0,0,0,0,0,0,0,0,0};
        __builtin_amdgcn_s_setprio(1);
#pragma unroll
        for (int dc = 0; dc < 4; ++dc) {
            const int ss = ((half * 8 + dc * 2 + lo) ^ lx) << 4;
            short8 k0 = *reinterpret_cast<const short8*>(Kb + l31 * 256 + ss);
            S = __builtin_amdgcn_mfma_f32_32x32x16_bf16(k0, qb4[dc], S, 0, 0, 0);
        }
        __builtin_amdgcn_s_setprio(0);

        short8 vf[2][2];
#pragma unroll
        for (int kc = 0; kc < 2; ++kc) {
#pragma unroll
            for (int dh = 0; dh < 2; ++dh) {
                const int sts = ((dh * 8 + (half * 2 + kc) * 2 + lo) ^ lx) << 4;
                vf[kc][dh] = *reinterpret_cast<const short8*>(Vb + l31 * 256 + sts);
            }
        }

        float s[16];
#pragma unroll
        for (int r = 0; r < 16; ++r) s[r] = S[r];

        if (blk == nb - 1) {
            const int q = qbase + l31;
#pragma unroll
            for (int r = 0; r < 16; ++r) {
                const int kk = kbase + half * 32 + (r & 3) + 8 * (r >> 2) + 4 * lo;
                s[r] = (kk <= q) ? s[r] : -INFINITY;
            }
        }

        float t0 = fmaxf(s[0], s[1]),  t1 = fmaxf(s[2], s[3]);
        float t2 = fmaxf(s[4], s[5]),  t3 = fmaxf(s[6], s[7]);
        float t4 = fmaxf(s[8], s[9]),  t5 = fmaxf(s[10], s[11]);
        float t6 = fmaxf(s[12], s[13]), t7 = fmaxf(s[14], s[15]);
        float lmax = fmaxf(fmaxf(fmaxf(t0, t1), fmaxf(t2, t3)),
                           fmaxf(fmaxf(t4, t5), fmaxf(t6, t7)));

        if (!__all(lmax - mrun <= 8.0f)) {
            float mx = fmaxf(lmax, __shfl_xor(lmax, 32));
            float mn = fmaxf(mrun, mx);
            float fsc = fexp2(mrun - mn);
            mrun = mn;
            lrun *= fsc;
#pragma unroll
            for (int r = 0; r < 16; ++r) {
                float fr = __shfl(fsc, (r & 3) + 8 * (r >> 2) + 4 * lo);
                oA[r] *= fr; oB[r] *= fr;
            }
        }

#pragma unroll
        for (int r = 0; r < 16; ++r) s[r] = fexp2(s[r] - mrun);

        float a0 = (s[0] + s[1]) + (s[2] + s[3]);
        float a1 = (s[4] + s[5]) + (s[6] + s[7]);
        float a2 = (s[8] + s[9]) + (s[10] + s[11]);
        float a3 = (s[12] + s[13]) + (s[14] + s[15]);
        float ps = (a0 + a1) + (a2 + a3);
        ps += __shfl_xor(ps, 32);
        lrun += ps;

        unsigned int pf[2][4];
        {
            unsigned int a0u = pk2b(s[0], s[1]);
            unsigned int b0u = pk2b(s[4], s[5]);
            swap32(a0u, b0u);
            unsigned int a1u = pk2b(s[2], s[3]);
            unsigned int b1u = pk2b(s[6], s[7]);
            swap32(a1u, b1u);
            pf[0][0] = a0u; pf[0][1] = a1u; pf[0][2] = b0u; pf[0][3] = b1u;
            unsigned int a2u = pk2b(s[8], s[9]);
            unsigned int b2u = pk2b(s[12], s[13]);
            swap32(a2u, b2u);
            unsigned int a3u = pk2b(s[10], s[11]);
            unsigned int b3u = pk2b(s[14], s[15]);
            swap32(a3u, b3u);
            pf[1][0] = a2u; pf[1][1] = a3u; pf[1][2] = b2u; pf[1][3] = b3u;
        }

        __builtin_amdgcn_s_setprio(1);
#pragma unroll
        for (int kc = 0; kc < 2; ++kc) {
            union { unsigned int u[4]; short8 v; } P;
            P.u[0] = pf[kc][0]; P.u[1] = pf[kc][1]; P.u[2] = pf[kc][2]; P.u[3] = pf[kc][3];
            oA = __builtin_amdgcn_mfma_f32_32x32x16_bf16(P.v, vf[kc][0], oA, 0, 0, 0);
            oB = __builtin_amdgcn_mfma_f32_32x32x16_bf16(P.v, vf[kc][1], oB, 0, 0, 0);
        }
        __builtin_amdgcn_s_setprio(0);

        __syncthreads();
        buf ^= 1;
    }

    // -------- pair merge: half0 publishes (m,l,O) via dead K/V LDS --------
    float* mbase = (tile == 0) ? (float*)&Kl[0][0] : (float*)&Vl[0][0];
    if (half == 0) {
#pragma unroll
        for (int g = 0; g < 8; ++g) {
            f32x4 w;
#pragma unroll
            for (int t = 0; t < 4; ++t)
                w[t] = (g < 4) ? oA[(g & 3) * 4 + t] : oB[(g & 3) * 4 + t];
            *reinterpret_cast<f32x4*>(mbase + lane * 32 + ((g ^ (lane & 7)) * 4)) = w;
        }
        if (lo == 0) {
            mbase[2048 + l31 * 2]     = mrun;
            mbase[2048 + l31 * 2 + 1] = lrun;
        }
    }
    __syncthreads();
    if (half == 1) {
        const float m0 = mbase[2048 + l31 * 2];
        const float l0 = mbase[2048 + l31 * 2 + 1];
        const float ms = fmaxf(m0, mrun);
        const float f0 = fexp2(m0 - ms);
        const float f1 = fexp2(mrun - ms);
        const float li = 1.0f / (l0 * f0 + lrun * f1);
#pragma unroll
        for (int g = 0; g < 8; ++g) {
            f32x4 rd = *reinterpret_cast<const f32x4*>(mbase + lane * 32 + ((g ^ (lane & 7)) * 4));
#pragma unroll
            for (int t = 0; t < 4; ++t) {
                const int r = (g & 3) * 4 + t;
                const float mine = (g < 4) ? oA[r] : oB[r];
                const int qr2 = (r & 3) + 8 * (r >> 2) + 4 * lo;
                const float f0q = __shfl(f0, qr2);
                const float f1q = __shfl(f1, qr2);
                const float liq = __shfl(li, qr2);
                const float val = (rd[t] * f0q + mine * f1q) * liq;
                const size_t rowoff = ((size_t)(b * SEQ + qbase + qr2)) * DM + h * DH + ((g < 4) ? 0 : 32);
                o[rowoff + l31] = f2b(val);
            }
        }
    }
}

// ---------------------------------------------------------------------------
extern "C" void kernel_launch(void* const* d_in, const int* in_sizes, int n_in,
                              void* d_out, int out_size, void* d_ws, size_t ws_size,
                              hipStream_t stream) {
    const float* x  = (const float*)d_in[0];
    const float* wq = (const float*)d_in[1];
    const float* wk = (const float*)d_in[2];
    const float* wv = (const float*)d_in[3];
    const float* wo = (const float*)d_in[4];
    float* out = (float*)d_out;

    char* ws = (char*)d_ws;
    const size_t MB = 1024 * 1024;
    unsigned short* xb      = (unsigned short*)(ws);             // 8 MB (reused for attn_bf)
    unsigned short* wqkv    = (unsigned short*)(ws + 8 * MB);    // 6 MB
    unsigned short* wob     = (unsigned short*)(ws + 14 * MB);   // 2 MB
    unsigned short* qkv     = (unsigned short*)(ws + 16 * MB);   // 24 MB
    unsigned short* vT      = (unsigned short*)(ws + 40 * MB);   // 8 MB
    float*          ropetab = (float*)(ws + 48 * MB);            // 512 KB
    unsigned short* attn_bf = xb;

    const int cvt_grid = (NX4 + 4 * NW4 + SEQ * 32) / 256;
    cvt_all<<<cvt_grid, 256, 0, stream>>>(x, wq, wk, wv, wo, xb, wqkv, wob, ropetab);

    gemm_qkv<<<dim3(DQKV / BN, MROWS / BM), 256, 0, stream>>>(xb, wqkv, qkv, vT, ropetab);

    attn_mfma<<<1024, 256, 0, stream>>>(qkv, vT, attn_bf);

    gemm_out<<<dim3(DM / 64, MROWS / 128), 256, 0, stream>>>(attn_bf, wob, out);
}